// Round 2
// baseline (1938.901 us; speedup 1.0000x reference)
//
#include <hip/hip_runtime.h>
#include <hip/hip_bf16.h>

#define NB 30

__device__ __forceinline__ float sigf(float x){ return 1.0f/(1.0f + expf(-x)); }

// ---------------------------------------------------------------------------
// Neighbor encoder: one block per (row, side). out[row*512 + side*256 + e]
// ---------------------------------------------------------------------------
__global__ __launch_bounds__(256) void neighbor_kernel(
    const int* __restrict__ connL, const int* __restrict__ connR,
    const float* __restrict__ emb, const float* __restrict__ naW,
    const float* __restrict__ naB, const float* __restrict__ nuW,
    const float* __restrict__ nuB, float* __restrict__ out)
{
    __shared__ __align__(16) float cat[NB][512];
    __shared__ float att[NB];
    __shared__ float partial[4][NB];
    __shared__ int ids[NB*2];

    const int t = threadIdx.x;
    const int row = blockIdx.x, side = blockIdx.y;
    const int* conn = (side ? connR : connL) + (size_t)row * (NB*2);

    if (t < NB*2) ids[t] = conn[t];
    __syncthreads();

    // gather rel/ent embeddings into cat, 16B chunks (4 floats)
    for (int i = t; i < NB*128; i += 256){
        int k = i >> 7, c = i & 127;
        int e0 = c * 4;
        int id  = (e0 < 256) ? ids[k*2+0] : ids[k*2+1];
        int off = e0 & 255;
        const float4* src = reinterpret_cast<const float4*>(emb + (size_t)id*256 + off);
        *reinterpret_cast<float4*>(&cat[k][e0]) = *src;
    }
    __syncthreads();

    // thread e = t computes out[k][e] = tanh(dot(cat[k], naW[e]) + naB[e]) for all k
    float acc[NB];
    #pragma unroll
    for (int k = 0; k < NB; k++) acc[k] = 0.f;
    const float4* wrow = reinterpret_cast<const float4*>(naW + (size_t)t * 512);
    for (int kc = 0; kc < 64; kc++){
        float4 w0 = wrow[kc*2], w1 = wrow[kc*2+1];
        #pragma unroll
        for (int k = 0; k < NB; k++){
            float4 c0 = *reinterpret_cast<const float4*>(&cat[k][kc*8]);
            float4 c1 = *reinterpret_cast<const float4*>(&cat[k][kc*8+4]);
            acc[k] += c0.x*w0.x + c0.y*w0.y + c0.z*w0.z + c0.w*w0.w
                    + c1.x*w1.x + c1.y*w1.y + c1.z*w1.z + c1.w*w1.w;
        }
    }

    const float nb = naB[t];
    const float nw = nuW[t];
    const int wave = t >> 6, lane = t & 63;
    #pragma unroll
    for (int k = 0; k < NB; k++){
        float v = tanhf(acc[k] + nb) * nw;
        v += __shfl_xor(v, 1);  v += __shfl_xor(v, 2);  v += __shfl_xor(v, 4);
        v += __shfl_xor(v, 8);  v += __shfl_xor(v, 16); v += __shfl_xor(v, 32);
        if (lane == 0) partial[wave][k] = v;
    }
    __syncthreads();
    if (t == 0){
        const float nub = nuB[0];
        float lg[NB], mx = -1e30f;
        #pragma unroll
        for (int k = 0; k < NB; k++){
            float L = partial[0][k] + partial[1][k] + partial[2][k] + partial[3][k] + nub;
            lg[k] = L; mx = fmaxf(mx, L);
        }
        float s = 0.f;
        #pragma unroll
        for (int k = 0; k < NB; k++){ float e = expf(lg[k]-mx); att[k] = e; s += e; }
        float inv = 1.f / s;
        #pragma unroll
        for (int k = 0; k < NB; k++) att[k] *= inv;
    }
    __syncthreads();

    float agg = 0.f;
    #pragma unroll
    for (int k = 0; k < NB; k++) agg += att[k] * cat[k][256 + t];
    out[(size_t)row*512 + side*256 + t] = tanhf(agg);
}

// ---------------------------------------------------------------------------
// Support encoder (MLP + residual + LayerNorm), 8 rows per block
// ---------------------------------------------------------------------------
__global__ __launch_bounds__(256) void support_enc_kernel(
    const float* __restrict__ X, int N,
    const float* __restrict__ p1W, const float* __restrict__ p1b,
    const float* __restrict__ p2W, const float* __restrict__ p2b,
    const float* __restrict__ lnA, const float* __restrict__ lnB,
    float* __restrict__ Y, float* __restrict__ Yout)
{
    __shared__ __align__(16) float xz[8][512];
    __shared__ __align__(16) float hb[8][1024];
    __shared__ float rs[8], rss[8];

    const int t = threadIdx.x;
    const int row0 = blockIdx.x * 8;

    for (int i = t; i < 8*512; i += 256){
        int r = i >> 9, e = i & 511;
        xz[r][e] = (row0 + r < N) ? X[(size_t)(row0+r)*512 + e] : 0.f;
    }
    if (t < 8){ rs[t] = 0.f; rss[t] = 0.f; }
    __syncthreads();

    // phase 1: h = relu(x @ p1W^T + p1b), 4 j's per thread
    {
        float acc[4][8] = {};
        for (int kc = 0; kc < 64; kc++){
            float4 w0[4], w1[4];
            #pragma unroll
            for (int ji = 0; ji < 4; ji++){
                const float4* wp = reinterpret_cast<const float4*>(p1W + (size_t)(t + (ji<<8))*512);
                w0[ji] = wp[kc*2]; w1[ji] = wp[kc*2+1];
            }
            #pragma unroll
            for (int r = 0; r < 8; r++){
                const float* xp = &xz[r][kc<<3];
                float4 a = *(const float4*)xp, b4 = *(const float4*)(xp+4);
                #pragma unroll
                for (int ji = 0; ji < 4; ji++){
                    acc[ji][r] += a.x*w0[ji].x + a.y*w0[ji].y + a.z*w0[ji].z + a.w*w0[ji].w
                                + b4.x*w1[ji].x + b4.y*w1[ji].y + b4.z*w1[ji].z + b4.w*w1[ji].w;
                }
            }
        }
        #pragma unroll
        for (int ji = 0; ji < 4; ji++){
            int j = t + (ji<<8);
            float bb = p1b[j];
            #pragma unroll
            for (int r = 0; r < 8; r++) hb[r][j] = fmaxf(acc[ji][r] + bb, 0.f);
        }
    }
    __syncthreads();

    // phase 2: z = h @ p2W^T + p2b + x, 2 e's per thread; keep z in regs
    float zs[2][8];
    {
        float acc[2][8] = {};
        for (int kc = 0; kc < 128; kc++){
            float4 w0[2], w1[2];
            #pragma unroll
            for (int ei = 0; ei < 2; ei++){
                const float4* wp = reinterpret_cast<const float4*>(p2W + (size_t)(t + (ei<<8))*1024);
                w0[ei] = wp[kc*2]; w1[ei] = wp[kc*2+1];
            }
            #pragma unroll
            for (int r = 0; r < 8; r++){
                const float* hp = &hb[r][kc<<3];
                float4 a = *(const float4*)hp, b4 = *(const float4*)(hp+4);
                #pragma unroll
                for (int ei = 0; ei < 2; ei++){
                    acc[ei][r] += a.x*w0[ei].x + a.y*w0[ei].y + a.z*w0[ei].z + a.w*w0[ei].w
                                + b4.x*w1[ei].x + b4.y*w1[ei].y + b4.z*w1[ei].z + b4.w*w1[ei].w;
                }
            }
        }
        #pragma unroll
        for (int ei = 0; ei < 2; ei++){
            int e = t + (ei<<8);
            float bb = p2b[e];
            #pragma unroll
            for (int r = 0; r < 8; r++) zs[ei][r] = acc[ei][r] + bb + xz[r][e];
        }
    }
    #pragma unroll
    for (int r = 0; r < 8; r++){
        float a = zs[0][r], b = zs[1][r];
        atomicAdd(&rs[r],  a + b);
        atomicAdd(&rss[r], a*a + b*b);
    }
    __syncthreads();

    #pragma unroll
    for (int ei = 0; ei < 2; ei++){
        int e = t + (ei<<8);
        float la = lnA[e], lb = lnB[e];
        #pragma unroll
        for (int r = 0; r < 8; r++){
            int row = row0 + r;
            if (row >= N) continue;
            float mu  = rs[r] * (1.f/512.f);
            float var = (rss[r] - 512.f*mu*mu) * (1.f/511.f);  // ddof=1
            float sd  = sqrtf(fmaxf(var, 0.f));
            float res = (zs[ei][r] - mu) / (sd + 1e-3f) * la + lb;
            Y[(size_t)row*512 + e] = res;
            if (Yout) Yout[(size_t)row*512 + e] = res;
        }
    }
}

// ---------------------------------------------------------------------------
// Small LSTM cell (D=512, batch=1): grid 32 x 16 d's, gates fused per-d
// ---------------------------------------------------------------------------
__global__ __launch_bounds__(256) void lstm_small(
    const float* __restrict__ x, const float* __restrict__ hin,
    float* __restrict__ c,
    const float* __restrict__ Wih, const float* __restrict__ Whh,
    const float* __restrict__ bih, const float* __restrict__ bhh,
    float* __restrict__ hout)
{
    __shared__ float xs[512], hs[512];
    __shared__ float gbuf[64];
    const int t = threadIdx.x;
    for (int i = t; i < 512; i += 256){ xs[i] = x[i]; hs[i] = hin[i]; }
    __syncthreads();

    const int dot = t >> 2, part = t & 3;
    const int gate = dot >> 4, dl = dot & 15;
    const int d = blockIdx.x * 16 + dl;
    const int j = gate * 512 + d;
    const float4* wi = reinterpret_cast<const float4*>(Wih + (size_t)j*512 + part*128);
    const float4* wh = reinterpret_cast<const float4*>(Whh + (size_t)j*512 + part*128);
    float acc = 0.f;
    for (int kc = 0; kc < 32; kc++){
        float4 w = wi[kc];
        const int kb = part*128 + kc*4;
        acc += xs[kb]*w.x + xs[kb+1]*w.y + xs[kb+2]*w.z + xs[kb+3]*w.w;
        float4 v = wh[kc];
        acc += hs[kb]*v.x + hs[kb+1]*v.y + hs[kb+2]*v.z + hs[kb+3]*v.w;
    }
    acc += __shfl_xor(acc, 1);
    acc += __shfl_xor(acc, 2);
    if (part == 0) gbuf[dot] = acc + bih[j] + bhh[j];
    __syncthreads();
    if (t < 16){
        int dd = blockIdx.x * 16 + t;
        float iv = gbuf[t], fv = gbuf[16+t], gv = gbuf[32+t], ov = gbuf[48+t];
        float cn = sigf(fv)*c[dd] + sigf(iv)*tanhf(gv);
        float hn = sigf(ov)*tanhf(cn);
        c[dd] = cn; hout[dd] = hn;
    }
}

// ---------------------------------------------------------------------------
// ae_loss + sge_enc (column sum; singleton softmax == 1)
// ---------------------------------------------------------------------------
__global__ __launch_bounds__(256) void finalize_kernel(
    const float* __restrict__ sg, const float* __restrict__ enc,
    const float* __restrict__ dec, float* __restrict__ sgeenc,
    float* __restrict__ outp)
{
    __shared__ float red[4];
    const int t = threadIdx.x;
    float s = 0.f;
    for (int i = t; i < 1536; i += 256){ float d = sg[i] - dec[i]; s += d*d; }
    s += __shfl_xor(s,1); s += __shfl_xor(s,2); s += __shfl_xor(s,4);
    s += __shfl_xor(s,8); s += __shfl_xor(s,16); s += __shfl_xor(s,32);
    if ((t & 63) == 0) red[t>>6] = s;
    __syncthreads();
    if (t == 0){
        float tot = (red[0]+red[1]+red[2]+red[3]) * (1.f/1536.f);
        outp[2048] = tot;
    }
    for (int d = t; d < 512; d += 256){
        float v = sg[d] + enc[d] + sg[512+d] + enc[512+d] + sg[1024+d] + enc[1024+d];
        sgeenc[d] = v;
        outp[2049 + d] = v;
    }
}

// ---------------------------------------------------------------------------
// wvec[n] = sum_j sge[j] * qWhh[wrow(n), 512+j]  (r-contribution, step-const)
// ---------------------------------------------------------------------------
__global__ __launch_bounds__(256) void wvec_kernel(
    const float* __restrict__ qWhh, const float* __restrict__ sge,
    float* __restrict__ wvec)
{
    __shared__ float ss[512];
    const int t = threadIdx.x;
    for (int i = t; i < 512; i += 256) ss[i] = sge[i];
    __syncthreads();
    const int n = blockIdx.x * 256 + t;
    const int row = ((n >> 9) << 10) + (n & 511);
    const float4* w = reinterpret_cast<const float4*>(qWhh + (size_t)row*1024 + 512);
    float acc = 0.f;
    for (int kc = 0; kc < 128; kc++){
        float4 wv = w[kc];
        const int kb = kc*4;
        acc += ss[kb]*wv.x + ss[kb+1]*wv.y + ss[kb+2]*wv.z + ss[kb+3]*wv.w;
    }
    wvec[n] = acc;
}

// ---------------------------------------------------------------------------
// GEMM: C[m,n] = sum_k A[m,k]*W[wrow(n),k] (+bias1+bias2)[wrow] (+addD)(+addV)
// M=N=2048, K=512, wrow(n) = (n>>9)*1024 + (n&511). 64x64 tile, 4x4/thread.
// ---------------------------------------------------------------------------
__global__ __launch_bounds__(256) void gemm_qsel(
    const float* __restrict__ A, const float* __restrict__ W, int ldw,
    const float* __restrict__ b1, const float* __restrict__ b2,
    const float* __restrict__ addD, const float* __restrict__ addV,
    float* __restrict__ C)
{
    __shared__ __align__(16) float As[16][68];
    __shared__ __align__(16) float Ws[16][68];
    const int t = threadIdx.x;
    const int tx = t & 15, ty = t >> 4;
    const int m0 = blockIdx.y * 64, n0 = blockIdx.x * 64;

    float acc[4][4] = {};

    const int lr = t >> 2, lc = t & 3;
    const int n = n0 + lr;
    const size_t wrow = (size_t)(((n >> 9) << 10) + (n & 511)) * (size_t)ldw;
    const float* Aptr = A + (size_t)(m0 + lr) * 512;

    for (int k0 = 0; k0 < 512; k0 += 16){
        float4 av = *reinterpret_cast<const float4*>(Aptr + k0 + lc*4);
        float4 wv = *reinterpret_cast<const float4*>(W + wrow + k0 + lc*4);
        __syncthreads();
        As[lc*4+0][lr] = av.x; As[lc*4+1][lr] = av.y;
        As[lc*4+2][lr] = av.z; As[lc*4+3][lr] = av.w;
        Ws[lc*4+0][lr] = wv.x; Ws[lc*4+1][lr] = wv.y;
        Ws[lc*4+2][lr] = wv.z; Ws[lc*4+3][lr] = wv.w;
        __syncthreads();
        #pragma unroll
        for (int kk = 0; kk < 16; kk++){
            float4 a4 = *reinterpret_cast<const float4*>(&As[kk][ty<<2]);
            float4 w4 = *reinterpret_cast<const float4*>(&Ws[kk][tx<<2]);
            acc[0][0]+=a4.x*w4.x; acc[0][1]+=a4.x*w4.y; acc[0][2]+=a4.x*w4.z; acc[0][3]+=a4.x*w4.w;
            acc[1][0]+=a4.y*w4.x; acc[1][1]+=a4.y*w4.y; acc[1][2]+=a4.y*w4.z; acc[1][3]+=a4.y*w4.w;
            acc[2][0]+=a4.z*w4.x; acc[2][1]+=a4.z*w4.y; acc[2][2]+=a4.z*w4.z; acc[2][3]+=a4.z*w4.w;
            acc[3][0]+=a4.w*w4.x; acc[3][1]+=a4.w*w4.y; acc[3][2]+=a4.w*w4.z; acc[3][3]+=a4.w*w4.w;
        }
    }

    float bj[4];
    #pragma unroll
    for (int j = 0; j < 4; j++){
        int nn = n0 + (tx<<2) + j;
        int br = ((nn >> 9) << 10) + (nn & 511);
        float v = 0.f;
        if (b1)   v += b1[br] + b2[br];
        if (addV) v += addV[nn];
        bj[j] = v;
    }
    #pragma unroll
    for (int i = 0; i < 4; i++){
        int m = m0 + (ty<<2) + i;
        const float* dRow = addD ? addD + (size_t)m*2048 : nullptr;
        float* cRow = C + (size_t)m*2048;
        #pragma unroll
        for (int j = 0; j < 4; j++){
            int nn = n0 + (tx<<2) + j;
            float v = acc[i][j] + bj[j];
            if (addD) v += dRow[nn];
            cRow[nn] = v;
        }
    }
}

// ---------------------------------------------------------------------------
// Gate math: c' = sig(f)*c + sig(i)*tanh(g);  h = qg + sig(o)*tanh(c')
// ---------------------------------------------------------------------------
__global__ __launch_bounds__(256) void gate_kernel(
    const float* __restrict__ G, const float* __restrict__ qg,
    float* __restrict__ c, float* __restrict__ h)
{
    const int idx = blockIdx.x * 256 + threadIdx.x;   // 2048*512
    const int b = idx >> 9, d = idx & 511;
    const float* g = G + (size_t)b * 2048;
    float iv = g[d], fv = g[512+d], gv = g[1024+d], ov = g[1536+d];
    float cn = sigf(fv)*c[idx] + sigf(iv)*tanhf(gv);
    float hn = qg[idx] + sigf(ov)*tanhf(cn);
    c[idx] = cn; h[idx] = hn;
}

// ---------------------------------------------------------------------------
// matching_scores[b] = dot(h[b], sge_enc)
// ---------------------------------------------------------------------------
__global__ __launch_bounds__(256) void scores_kernel(
    const float* __restrict__ h, const float* __restrict__ sge,
    float* __restrict__ out)
{
    const int wave = threadIdx.x >> 6, lane = threadIdx.x & 63;
    const int row = blockIdx.x * 4 + wave;
    const float* hr = h + (size_t)row * 512;
    float s = 0.f;
    for (int i = lane; i < 512; i += 64) s += hr[i] * sge[i];
    s += __shfl_xor(s,1); s += __shfl_xor(s,2); s += __shfl_xor(s,4);
    s += __shfl_xor(s,8); s += __shfl_xor(s,16); s += __shfl_xor(s,32);
    if (lane == 0) out[row] = s;
}

// ---------------------------------------------------------------------------
extern "C" void kernel_launch(void* const* d_in, const int* in_sizes, int n_in,
                              void* d_out, int out_size, void* d_ws, size_t ws_size,
                              hipStream_t stream)
{
    (void)in_sizes; (void)n_in; (void)out_size; (void)ws_size;

    const int* qlc = (const int*)d_in[2];
    const int* qrc = (const int*)d_in[4];
    const int* slc = (const int*)d_in[6];
    const int* src = (const int*)d_in[8];
    const float* emb = (const float*)d_in[10];
    const float* naW = (const float*)d_in[11];
    const float* naB = (const float*)d_in[12];
    const float* nuW = (const float*)d_in[13];
    const float* nuB = (const float*)d_in[14];
    const float* p1W = (const float*)d_in[15], *p1b = (const float*)d_in[16];
    const float* p2W = (const float*)d_in[17], *p2b = (const float*)d_in[18];
    const float* lnA = (const float*)d_in[19], *lnB = (const float*)d_in[20];
    const float* eWih = (const float*)d_in[21], *eWhh = (const float*)d_in[22];
    const float* eBih = (const float*)d_in[23], *eBhh = (const float*)d_in[24];
    const float* dWih = (const float*)d_in[25], *dWhh = (const float*)d_in[26];
    const float* dBih = (const float*)d_in[27], *dBhh = (const float*)d_in[28];
    const float* qWih = (const float*)d_in[33], *qWhh = (const float*)d_in[34];
    const float* qBih = (const float*)d_in[35], *qBhh = (const float*)d_in[36];
    float* out = (float*)d_out;

    float* w = (float*)d_ws;
    size_t off = 0;
    auto alloc = [&](size_t nelem){ float* p = w + off; off += nelem; return p; };
    float* qn   = alloc(2048ull*512);   // query neighbor [2048,512]
    float* qg   = alloc(2048ull*512);   // query_g
    float* sn   = alloc(1536);          // support neighbor [3,512]
    float* sg   = alloc(1536);          // support_g [3,512]
    float* enc  = alloc(1536);          // enc_out [3,512]
    float* dec  = alloc(1536);          // decoder_set [3,512]
    float* zc   = alloc(1024);          // zbuf(512) + c_state(512)
    float* sgee = alloc(512);           // support_g_encoder
    float* wv   = alloc(2048);          // r @ WhhR^T (selected)
    float* base = alloc(2048ull*2048);  // qg @ WihSel^T + biases
    float* G    = alloc(2048ull*2048);  // per-step gates
    float* hb   = alloc(2048ull*512);   // h
    float* cb   = alloc(2048ull*512);   // c[:, :512]
    float* zbuf = zc;
    float* cst  = zc + 512;

    hipMemsetAsync(zc, 0, 1024*sizeof(float), stream);
    hipMemsetAsync(cb, 0, 2048ull*512*sizeof(float), stream);

    // neighbor encoders
    neighbor_kernel<<<dim3(2048,2), 256, 0, stream>>>(qlc, qrc, emb, naW, naB, nuW, nuB, qn);
    neighbor_kernel<<<dim3(3,2),    256, 0, stream>>>(slc, src, emb, naW, naB, nuW, nuB, sn);

    // support encoder (query_g also written to out[2561:])
    support_enc_kernel<<<256, 256, 0, stream>>>(qn, 2048, p1W, p1b, p2W, p2b, lnA, lnB, qg, out + 2561);
    support_enc_kernel<<<1,   256, 0, stream>>>(sn, 3,    p1W, p1b, p2W, p2b, lnA, lnB, sg, nullptr);

    // set autoencoder: enc chain then dec chain
    lstm_small<<<32, 256, 0, stream>>>(sg,        zbuf,      cst, eWih, eWhh, eBih, eBhh, enc);
    lstm_small<<<32, 256, 0, stream>>>(sg + 512,  enc,       cst, eWih, eWhh, eBih, eBhh, enc + 512);
    lstm_small<<<32, 256, 0, stream>>>(sg + 1024, enc + 512, cst, eWih, eWhh, eBih, eBhh, enc + 1024);
    lstm_small<<<32, 256, 0, stream>>>(enc + 1024, enc + 1024, cst, dWih, dWhh, dBih, dBhh, dec);
    lstm_small<<<32, 256, 0, stream>>>(dec,        dec,        cst, dWih, dWhh, dBih, dBhh, dec + 512);
    lstm_small<<<32, 256, 0, stream>>>(dec + 512,  dec + 512,  cst, dWih, dWhh, dBih, dBhh, dec + 1024);

    // ae_loss + support_g_encoder
    finalize_kernel<<<1, 256, 0, stream>>>(sg, enc, dec, sgee, out);

    // constant r-contribution to gates
    wvec_kernel<<<8, 256, 0, stream>>>(qWhh, sgee, wv);

    // query encoder: base = qg @ WihSel^T + biases; then 4 steps (live half only)
    gemm_qsel<<<dim3(32,32), 256, 0, stream>>>(qg, qWih, 512, qBih, qBhh, nullptr, nullptr, base);
    gate_kernel<<<4096, 256, 0, stream>>>(base, qg, cb, hb);   // step 1 (h_r = 0)
    for (int s = 0; s < 3; s++){
        gemm_qsel<<<dim3(32,32), 256, 0, stream>>>(hb, qWhh, 1024, nullptr, nullptr, base, wv, G);
        gate_kernel<<<4096, 256, 0, stream>>>(G, qg, cb, hb);
    }

    // matching_scores
    scores_kernel<<<512, 256, 0, stream>>>(hb, sgee, out);
}

// Round 3
// 981.716 us; speedup vs baseline: 1.9750x; 1.9750x over previous
//
#include <hip/hip_runtime.h>
#include <hip/hip_bf16.h>

#define NB 30

typedef __attribute__((ext_vector_type(8))) short bf16x8;
typedef __attribute__((ext_vector_type(4))) float f32x4;
#define MFMA16(a,b,c) __builtin_amdgcn_mfma_f32_16x16x32_bf16(a,b,c,0,0,0)

__device__ __forceinline__ float sigf(float x){ return 1.0f/(1.0f + __expf(-x)); }
__device__ __forceinline__ float ftanh(float x){
    float ax = fabsf(x);
    float e = __expf(-2.f*ax);
    float r = (1.f - e) / (1.f + e);
    return copysignf(r, x);
}
__device__ __forceinline__ unsigned short f2b(float f){
    unsigned u = __float_as_uint(f);
    u += 0x7fffu + ((u >> 16) & 1u);
    return (unsigned short)(u >> 16);
}
__device__ __forceinline__ unsigned int pk2(float x, float y){
    return ((unsigned)f2b(y) << 16) | (unsigned)f2b(x);
}
__device__ __forceinline__ float b2f(unsigned short u){
    return __uint_as_float(((unsigned int)u) << 16);
}

// ---------------------------------------------------------------------------
// naW f32 -> bf16 (once per launch). 256x512 = 131072 elems.
// ---------------------------------------------------------------------------
__global__ __launch_bounds__(256) void cvt_naW(const float* __restrict__ src,
                                               unsigned short* __restrict__ dst){
    int i = blockIdx.x * 256 + threadIdx.x;
    dst[i] = f2b(src[i]);
}

// ---------------------------------------------------------------------------
// Neighbor encoder, MFMA version. One block per (row, side).
// S[30,256] = cat[30,512] @ naW^T ; logits -> softmax(30) -> agg -> tanh.
// ---------------------------------------------------------------------------
#define CATP 520
__global__ __launch_bounds__(256) void neighbor_mfma(
    const int* __restrict__ connL, const int* __restrict__ connR,
    const float* __restrict__ emb, const unsigned short* __restrict__ naWbf,
    const float* __restrict__ naB, const float* __restrict__ nuW,
    const float* __restrict__ nuB, float* __restrict__ out)
{
    __shared__ __align__(16) unsigned short cat[32][CATP];
    __shared__ float logit[32];
    __shared__ float att[NB];
    __shared__ int ids[NB*2];

    const int t = threadIdx.x;
    const int row = blockIdx.x, side = blockIdx.y;
    const int* conn = (side ? connR : connL) + (size_t)row * (NB*2);

    if (t < NB*2) ids[t] = conn[t];
    if (t >= 64 && t < 96) logit[t - 64] = 0.f;
    __syncthreads();

    // gather + f32->bf16: 30 rows x 512 (rel | ent)
    for (int i = t; i < NB*128; i += 256){
        int k = i >> 7, e0 = (i & 127) * 4;
        int id  = (e0 < 256) ? ids[k*2] : ids[k*2+1];
        float4 v = *reinterpret_cast<const float4*>(emb + (size_t)id*256 + (e0 & 255));
        uint2 s; s.x = pk2(v.x, v.y); s.y = pk2(v.z, v.w);
        *reinterpret_cast<uint2*>(&cat[k][e0]) = s;
    }
    // zero pad rows 30,31
    for (int i = t; i < 2*128; i += 256){
        int k = 30 + (i >> 7), e0 = (i & 127) * 4;
        uint2 z; z.x = 0u; z.y = 0u;
        *reinterpret_cast<uint2*>(&cat[k][e0]) = z;
    }
    __syncthreads();

    const int w = t >> 6, lane = t & 63;
    const int col = lane & 15, quad = lane >> 4;

    f32x4 acc[2][4] = {};
    for (int ks = 0; ks < 16; ks++){
        const int k0 = ks*32 + quad*8;
        bf16x8 a0 = *reinterpret_cast<const bf16x8*>(&cat[col][k0]);
        bf16x8 a1 = *reinterpret_cast<const bf16x8*>(&cat[16 + col][k0]);
        #pragma unroll
        for (int i = 0; i < 4; i++){
            int n = (w*4 + i)*16 + col;
            bf16x8 b = *reinterpret_cast<const bf16x8*>(naWbf + (size_t)n*512 + k0);
            acc[0][i] = MFMA16(a0, b, acc[0][i]);
            acc[1][i] = MFMA16(a1, b, acc[1][i]);
        }
    }

    // logits: val[m] += tanh(S[m][n]+naB[n]) * nuW[n], reduce over n
    float nu[4], nbv[4];
    #pragma unroll
    for (int i = 0; i < 4; i++){
        int n = (w*4 + i)*16 + col;
        nu[i] = nuW[n]; nbv[i] = naB[n];
    }
    #pragma unroll
    for (int mt = 0; mt < 2; mt++){
        #pragma unroll
        for (int r = 0; r < 4; r++){
            int m = mt*16 + quad*4 + r;
            float v = 0.f;
            #pragma unroll
            for (int i = 0; i < 4; i++)
                v += ftanh(acc[mt][i][r] + nbv[i]) * nu[i];
            v += __shfl_xor(v, 1); v += __shfl_xor(v, 2);
            v += __shfl_xor(v, 4); v += __shfl_xor(v, 8);
            if (col == 0 && m < NB) atomicAdd(&logit[m], v);
        }
    }
    __syncthreads();

    if (t == 0){
        const float nub = nuB[0];
        float mx = -1e30f;
        for (int k = 0; k < NB; k++){
            float L = logit[k] + nub;
            logit[k] = L; mx = fmaxf(mx, L);
        }
        float s = 0.f;
        for (int k = 0; k < NB; k++){ float e = __expf(logit[k] - mx); att[k] = e; s += e; }
        float inv = 1.f / s;
        for (int k = 0; k < NB; k++) att[k] *= inv;
    }
    __syncthreads();

    float agg = 0.f;
    #pragma unroll
    for (int k = 0; k < NB; k++) agg += att[k] * b2f(cat[k][256 + t]);
    out[(size_t)row*512 + side*256 + t] = ftanh(agg);
}

// ---------------------------------------------------------------------------
// Support encoder (MLP + residual + LayerNorm), 8 rows per block (fp32)
// ---------------------------------------------------------------------------
__global__ __launch_bounds__(256) void support_enc_kernel(
    const float* __restrict__ X, int N,
    const float* __restrict__ p1W, const float* __restrict__ p1b,
    const float* __restrict__ p2W, const float* __restrict__ p2b,
    const float* __restrict__ lnA, const float* __restrict__ lnB,
    float* __restrict__ Y, float* __restrict__ Yout)
{
    __shared__ __align__(16) float xz[8][512];
    __shared__ __align__(16) float hb[8][1024];
    __shared__ float rs[8], rss[8];

    const int t = threadIdx.x;
    const int row0 = blockIdx.x * 8;

    for (int i = t; i < 8*512; i += 256){
        int r = i >> 9, e = i & 511;
        xz[r][e] = (row0 + r < N) ? X[(size_t)(row0+r)*512 + e] : 0.f;
    }
    if (t < 8){ rs[t] = 0.f; rss[t] = 0.f; }
    __syncthreads();

    {
        float acc[4][8] = {};
        for (int kc = 0; kc < 64; kc++){
            float4 w0[4], w1[4];
            #pragma unroll
            for (int ji = 0; ji < 4; ji++){
                const float4* wp = reinterpret_cast<const float4*>(p1W + (size_t)(t + (ji<<8))*512);
                w0[ji] = wp[kc*2]; w1[ji] = wp[kc*2+1];
            }
            #pragma unroll
            for (int r = 0; r < 8; r++){
                const float* xp = &xz[r][kc<<3];
                float4 a = *(const float4*)xp, b4 = *(const float4*)(xp+4);
                #pragma unroll
                for (int ji = 0; ji < 4; ji++){
                    acc[ji][r] += a.x*w0[ji].x + a.y*w0[ji].y + a.z*w0[ji].z + a.w*w0[ji].w
                                + b4.x*w1[ji].x + b4.y*w1[ji].y + b4.z*w1[ji].z + b4.w*w1[ji].w;
                }
            }
        }
        #pragma unroll
        for (int ji = 0; ji < 4; ji++){
            int j = t + (ji<<8);
            float bb = p1b[j];
            #pragma unroll
            for (int r = 0; r < 8; r++) hb[r][j] = fmaxf(acc[ji][r] + bb, 0.f);
        }
    }
    __syncthreads();

    float zs[2][8];
    {
        float acc[2][8] = {};
        for (int kc = 0; kc < 128; kc++){
            float4 w0[2], w1[2];
            #pragma unroll
            for (int ei = 0; ei < 2; ei++){
                const float4* wp = reinterpret_cast<const float4*>(p2W + (size_t)(t + (ei<<8))*1024);
                w0[ei] = wp[kc*2]; w1[ei] = wp[kc*2+1];
            }
            #pragma unroll
            for (int r = 0; r < 8; r++){
                const float* hp = &hb[r][kc<<3];
                float4 a = *(const float4*)hp, b4 = *(const float4*)(hp+4);
                #pragma unroll
                for (int ei = 0; ei < 2; ei++){
                    acc[ei][r] += a.x*w0[ei].x + a.y*w0[ei].y + a.z*w0[ei].z + a.w*w0[ei].w
                                + b4.x*w1[ei].x + b4.y*w1[ei].y + b4.z*w1[ei].z + b4.w*w1[ei].w;
                }
            }
        }
        #pragma unroll
        for (int ei = 0; ei < 2; ei++){
            int e = t + (ei<<8);
            float bb = p2b[e];
            #pragma unroll
            for (int r = 0; r < 8; r++) zs[ei][r] = acc[ei][r] + bb + xz[r][e];
        }
    }
    #pragma unroll
    for (int r = 0; r < 8; r++){
        float a = zs[0][r], b = zs[1][r];
        atomicAdd(&rs[r],  a + b);
        atomicAdd(&rss[r], a*a + b*b);
    }
    __syncthreads();

    #pragma unroll
    for (int ei = 0; ei < 2; ei++){
        int e = t + (ei<<8);
        float la = lnA[e], lb = lnB[e];
        #pragma unroll
        for (int r = 0; r < 8; r++){
            int row = row0 + r;
            if (row >= N) continue;
            float mu  = rs[r] * (1.f/512.f);
            float var = (rss[r] - 512.f*mu*mu) * (1.f/511.f);  // ddof=1
            float sd  = sqrtf(fmaxf(var, 0.f));
            float res = (zs[ei][r] - mu) / (sd + 1e-3f) * la + lb;
            Y[(size_t)row*512 + e] = res;
            if (Yout) Yout[(size_t)row*512 + e] = res;
        }
    }
}

// ---------------------------------------------------------------------------
// Small LSTM cell (D=512, batch=1)
// ---------------------------------------------------------------------------
__global__ __launch_bounds__(256) void lstm_small(
    const float* __restrict__ x, const float* __restrict__ hin,
    float* __restrict__ c,
    const float* __restrict__ Wih, const float* __restrict__ Whh,
    const float* __restrict__ bih, const float* __restrict__ bhh,
    float* __restrict__ hout)
{
    __shared__ float xs[512], hs[512];
    __shared__ float gbuf[64];
    const int t = threadIdx.x;
    for (int i = t; i < 512; i += 256){ xs[i] = x[i]; hs[i] = hin[i]; }
    __syncthreads();

    const int dot = t >> 2, part = t & 3;
    const int gate = dot >> 4, dl = dot & 15;
    const int d = blockIdx.x * 16 + dl;
    const int j = gate * 512 + d;
    const float4* wi = reinterpret_cast<const float4*>(Wih + (size_t)j*512 + part*128);
    const float4* wh = reinterpret_cast<const float4*>(Whh + (size_t)j*512 + part*128);
    float acc = 0.f;
    for (int kc = 0; kc < 32; kc++){
        float4 w = wi[kc];
        const int kb = part*128 + kc*4;
        acc += xs[kb]*w.x + xs[kb+1]*w.y + xs[kb+2]*w.z + xs[kb+3]*w.w;
        float4 v = wh[kc];
        acc += hs[kb]*v.x + hs[kb+1]*v.y + hs[kb+2]*v.z + hs[kb+3]*v.w;
    }
    acc += __shfl_xor(acc, 1);
    acc += __shfl_xor(acc, 2);
    if (part == 0) gbuf[dot] = acc + bih[j] + bhh[j];
    __syncthreads();
    if (t < 16){
        int dd = blockIdx.x * 16 + t;
        float iv = gbuf[t], fv = gbuf[16+t], gv = gbuf[32+t], ov = gbuf[48+t];
        float cn = sigf(fv)*c[dd] + sigf(iv)*ftanh(gv);
        float hn = sigf(ov)*ftanh(cn);
        c[dd] = cn; hout[dd] = hn;
    }
}

// ---------------------------------------------------------------------------
// ae_loss + sge_enc (singleton softmax == 1)
// ---------------------------------------------------------------------------
__global__ __launch_bounds__(256) void finalize_kernel(
    const float* __restrict__ sg, const float* __restrict__ enc,
    const float* __restrict__ dec, float* __restrict__ sgeenc,
    float* __restrict__ outp)
{
    __shared__ float red[4];
    const int t = threadIdx.x;
    float s = 0.f;
    for (int i = t; i < 1536; i += 256){ float d = sg[i] - dec[i]; s += d*d; }
    s += __shfl_xor(s,1); s += __shfl_xor(s,2); s += __shfl_xor(s,4);
    s += __shfl_xor(s,8); s += __shfl_xor(s,16); s += __shfl_xor(s,32);
    if ((t & 63) == 0) red[t>>6] = s;
    __syncthreads();
    if (t == 0){
        float tot = (red[0]+red[1]+red[2]+red[3]) * (1.f/1536.f);
        outp[2048] = tot;
    }
    for (int d = t; d < 512; d += 256){
        float v = sg[d] + enc[d] + sg[512+d] + enc[512+d] + sg[1024+d] + enc[1024+d];
        sgeenc[d] = v;
        outp[2049 + d] = v;
    }
}

// ---------------------------------------------------------------------------
// wvec[n] = sum_j sge[j] * qWhh[wrow(n), 512+j]
// ---------------------------------------------------------------------------
__global__ __launch_bounds__(256) void wvec_kernel(
    const float* __restrict__ qWhh, const float* __restrict__ sge,
    float* __restrict__ wvec)
{
    __shared__ float ss[512];
    const int t = threadIdx.x;
    for (int i = t; i < 512; i += 256) ss[i] = sge[i];
    __syncthreads();
    const int n = blockIdx.x * 256 + t;
    const int row = ((n >> 9) << 10) + (n & 511);
    const float4* w = reinterpret_cast<const float4*>(qWhh + (size_t)row*1024 + 512);
    float acc = 0.f;
    for (int kc = 0; kc < 128; kc++){
        float4 wv = w[kc];
        const int kb = kc*4;
        acc += ss[kb]*wv.x + ss[kb+1]*wv.y + ss[kb+2]*wv.z + ss[kb+3]*wv.w;
    }
    wvec[n] = acc;
}

// ---------------------------------------------------------------------------
// MFMA GEMM: C[m,n] = sum_k A[m,k]*W[wrow(n),k] (+b1+b2)[wrow] (+addD)(+addV)
// M=N=2048, K=512. Block tile 64x64, 4 waves of 32x32. f32->bf16 staged LDS.
// ---------------------------------------------------------------------------
__global__ __launch_bounds__(256) void gemm_mfma(
    const float* __restrict__ A, const float* __restrict__ W, int ldw,
    const float* __restrict__ b1, const float* __restrict__ b2,
    const float* __restrict__ addD, const float* __restrict__ addV,
    float* __restrict__ C)
{
    __shared__ __align__(16) unsigned short As[64][72];
    __shared__ __align__(16) unsigned short Bs[64][72];
    const int t = threadIdx.x;
    const int m0 = blockIdx.y * 64, n0 = blockIdx.x * 64;
    const int w = t >> 6, lane = t & 63;
    const int col = lane & 15, quad = lane >> 4;
    const int wm = (w & 1) * 32, wn = (w >> 1) * 32;

    const int sr = t >> 2;
    const int sc = (t & 3) * 16;
    const float* Arow = A + (size_t)(m0 + sr)*512 + sc;
    const int nglob = n0 + sr;
    const size_t wr = (size_t)(((nglob >> 9) << 10) + (nglob & 511)) * (size_t)ldw;
    const float* Wrow = W + wr + sc;

    f32x4 acc[2][2] = {};

    for (int kc = 0; kc < 8; kc++){
        float4 a0 = *reinterpret_cast<const float4*>(Arow + kc*64 + 0);
        float4 a1 = *reinterpret_cast<const float4*>(Arow + kc*64 + 4);
        float4 a2 = *reinterpret_cast<const float4*>(Arow + kc*64 + 8);
        float4 a3 = *reinterpret_cast<const float4*>(Arow + kc*64 + 12);
        float4 b0 = *reinterpret_cast<const float4*>(Wrow + kc*64 + 0);
        float4 b1v = *reinterpret_cast<const float4*>(Wrow + kc*64 + 4);
        float4 b2v = *reinterpret_cast<const float4*>(Wrow + kc*64 + 8);
        float4 b3v = *reinterpret_cast<const float4*>(Wrow + kc*64 + 12);
        __syncthreads();
        {
            unsigned short* ap = &As[sr][sc];
            uint2 s;
            s.x = pk2(a0.x,a0.y); s.y = pk2(a0.z,a0.w); *reinterpret_cast<uint2*>(ap+0)  = s;
            s.x = pk2(a1.x,a1.y); s.y = pk2(a1.z,a1.w); *reinterpret_cast<uint2*>(ap+4)  = s;
            s.x = pk2(a2.x,a2.y); s.y = pk2(a2.z,a2.w); *reinterpret_cast<uint2*>(ap+8)  = s;
            s.x = pk2(a3.x,a3.y); s.y = pk2(a3.z,a3.w); *reinterpret_cast<uint2*>(ap+12) = s;
            unsigned short* bp = &Bs[sr][sc];
            s.x = pk2(b0.x,b0.y); s.y = pk2(b0.z,b0.w); *reinterpret_cast<uint2*>(bp+0)  = s;
            s.x = pk2(b1v.x,b1v.y); s.y = pk2(b1v.z,b1v.w); *reinterpret_cast<uint2*>(bp+4)  = s;
            s.x = pk2(b2v.x,b2v.y); s.y = pk2(b2v.z,b2v.w); *reinterpret_cast<uint2*>(bp+8)  = s;
            s.x = pk2(b3v.x,b3v.y); s.y = pk2(b3v.z,b3v.w); *reinterpret_cast<uint2*>(bp+12) = s;
        }
        __syncthreads();
        #pragma unroll
        for (int ks = 0; ks < 2; ks++){
            const int k0 = ks*32 + quad*8;
            bf16x8 fa0 = *reinterpret_cast<const bf16x8*>(&As[wm + col][k0]);
            bf16x8 fa1 = *reinterpret_cast<const bf16x8*>(&As[wm + 16 + col][k0]);
            bf16x8 fb0 = *reinterpret_cast<const bf16x8*>(&Bs[wn + col][k0]);
            bf16x8 fb1 = *reinterpret_cast<const bf16x8*>(&Bs[wn + 16 + col][k0]);
            acc[0][0] = MFMA16(fa0, fb0, acc[0][0]);
            acc[0][1] = MFMA16(fa0, fb1, acc[0][1]);
            acc[1][0] = MFMA16(fa1, fb0, acc[1][0]);
            acc[1][1] = MFMA16(fa1, fb1, acc[1][1]);
        }
    }

    #pragma unroll
    for (int mt = 0; mt < 2; mt++){
        #pragma unroll
        for (int nt = 0; nt < 2; nt++){
            #pragma unroll
            for (int r = 0; r < 4; r++){
                int m = m0 + wm + mt*16 + quad*4 + r;
                int n = n0 + wn + nt*16 + col;
                float v = acc[mt][nt][r];
                if (b1){
                    int br = ((n >> 9) << 10) + (n & 511);
                    v += b1[br] + b2[br];
                }
                if (addV) v += addV[n];
                if (addD) v += addD[(size_t)m*2048 + n];
                C[(size_t)m*2048 + n] = v;
            }
        }
    }
}

// ---------------------------------------------------------------------------
// Gate math: c' = sig(f)*c + sig(i)*tanh(g);  h = qg + sig(o)*tanh(c')
// ---------------------------------------------------------------------------
__global__ __launch_bounds__(256) void gate_kernel(
    const float* __restrict__ G, const float* __restrict__ qg,
    float* __restrict__ c, float* __restrict__ h)
{
    const int idx = blockIdx.x * 256 + threadIdx.x;
    const int b = idx >> 9, d = idx & 511;
    const float* g = G + (size_t)b * 2048;
    float iv = g[d], fv = g[512+d], gv = g[1024+d], ov = g[1536+d];
    float cn = sigf(fv)*c[idx] + sigf(iv)*ftanh(gv);
    float hn = qg[idx] + sigf(ov)*ftanh(cn);
    c[idx] = cn; h[idx] = hn;
}

// ---------------------------------------------------------------------------
// matching_scores[b] = dot(h[b], sge_enc)
// ---------------------------------------------------------------------------
__global__ __launch_bounds__(256) void scores_kernel(
    const float* __restrict__ h, const float* __restrict__ sge,
    float* __restrict__ out)
{
    const int wave = threadIdx.x >> 6, lane = threadIdx.x & 63;
    const int row = blockIdx.x * 4 + wave;
    const float* hr = h + (size_t)row * 512;
    float s = 0.f;
    for (int i = lane; i < 512; i += 64) s += hr[i] * sge[i];
    s += __shfl_xor(s,1); s += __shfl_xor(s,2); s += __shfl_xor(s,4);
    s += __shfl_xor(s,8); s += __shfl_xor(s,16); s += __shfl_xor(s,32);
    if (lane == 0) out[row] = s;
}

// ---------------------------------------------------------------------------
extern "C" void kernel_launch(void* const* d_in, const int* in_sizes, int n_in,
                              void* d_out, int out_size, void* d_ws, size_t ws_size,
                              hipStream_t stream)
{
    (void)in_sizes; (void)n_in; (void)out_size; (void)ws_size;

    const int* qlc = (const int*)d_in[2];
    const int* qrc = (const int*)d_in[4];
    const int* slc = (const int*)d_in[6];
    const int* src = (const int*)d_in[8];
    const float* emb = (const float*)d_in[10];
    const float* naW = (const float*)d_in[11];
    const float* naB = (const float*)d_in[12];
    const float* nuW = (const float*)d_in[13];
    const float* nuB = (const float*)d_in[14];
    const float* p1W = (const float*)d_in[15], *p1b = (const float*)d_in[16];
    const float* p2W = (const float*)d_in[17], *p2b = (const float*)d_in[18];
    const float* lnA = (const float*)d_in[19], *lnB = (const float*)d_in[20];
    const float* eWih = (const float*)d_in[21], *eWhh = (const float*)d_in[22];
    const float* eBih = (const float*)d_in[23], *eBhh = (const float*)d_in[24];
    const float* dWih = (const float*)d_in[25], *dWhh = (const float*)d_in[26];
    const float* dBih = (const float*)d_in[27], *dBhh = (const float*)d_in[28];
    const float* qWih = (const float*)d_in[33], *qWhh = (const float*)d_in[34];
    const float* qBih = (const float*)d_in[35], *qBhh = (const float*)d_in[36];
    float* out = (float*)d_out;

    float* w = (float*)d_ws;
    size_t off = 0;
    auto alloc = [&](size_t nelem){ float* p = w + off; off += nelem; return p; };
    float* qn   = alloc(2048ull*512);   // query neighbor [2048,512]
    float* qg   = alloc(2048ull*512);   // query_g
    float* sn   = alloc(1536);          // support neighbor [3,512]
    float* sg   = alloc(1536);          // support_g [3,512]
    float* enc  = alloc(1536);          // enc_out [3,512]
    float* dec  = alloc(1536);          // decoder_set [3,512]
    float* zc   = alloc(1024);          // zbuf(512) + c_state(512)
    float* sgee = alloc(512);           // support_g_encoder
    float* wv   = alloc(2048);          // r @ WhhR^T (selected)
    float* naWb = alloc(65536);         // naW bf16 (131072 u16)
    float* base = alloc(2048ull*2048);  // qg @ WihSel^T + biases
    float* G    = alloc(2048ull*2048);  // per-step gates
    float* hb   = alloc(2048ull*512);   // h
    float* cb   = alloc(2048ull*512);   // c[:, :512]
    float* zbuf = zc;
    float* cst  = zc + 512;
    unsigned short* naWbf = (unsigned short*)naWb;

    hipMemsetAsync(zc, 0, 1024*sizeof(float), stream);
    hipMemsetAsync(cb, 0, 2048ull*512*sizeof(float), stream);

    cvt_naW<<<512, 256, 0, stream>>>(naW, naWbf);

    // neighbor encoders (MFMA)
    neighbor_mfma<<<dim3(2048,2), 256, 0, stream>>>(qlc, qrc, emb, naWbf, naB, nuW, nuB, qn);
    neighbor_mfma<<<dim3(3,2),    256, 0, stream>>>(slc, src, emb, naWbf, naB, nuW, nuB, sn);

    // support encoder (query_g also written to out[2561:])
    support_enc_kernel<<<256, 256, 0, stream>>>(qn, 2048, p1W, p1b, p2W, p2b, lnA, lnB, qg, out + 2561);
    support_enc_kernel<<<1,   256, 0, stream>>>(sn, 3,    p1W, p1b, p2W, p2b, lnA, lnB, sg, nullptr);

    // set autoencoder: enc chain then dec chain
    lstm_small<<<32, 256, 0, stream>>>(sg,        zbuf,      cst, eWih, eWhh, eBih, eBhh, enc);
    lstm_small<<<32, 256, 0, stream>>>(sg + 512,  enc,       cst, eWih, eWhh, eBih, eBhh, enc + 512);
    lstm_small<<<32, 256, 0, stream>>>(sg + 1024, enc + 512, cst, eWih, eWhh, eBih, eBhh, enc + 1024);
    lstm_small<<<32, 256, 0, stream>>>(enc + 1024, enc + 1024, cst, dWih, dWhh, dBih, dBhh, dec);
    lstm_small<<<32, 256, 0, stream>>>(dec,        dec,        cst, dWih, dWhh, dBih, dBhh, dec + 512);
    lstm_small<<<32, 256, 0, stream>>>(dec + 512,  dec + 512,  cst, dWih, dWhh, dBih, dBhh, dec + 1024);

    // ae_loss + support_g_encoder
    finalize_kernel<<<1, 256, 0, stream>>>(sg, enc, dec, sgee, out);

    // constant r-contribution to gates
    wvec_kernel<<<8, 256, 0, stream>>>(qWhh, sgee, wv);

    // query encoder: base = qg @ WihSel^T + biases; 4 steps (live half only)
    gemm_mfma<<<dim3(32,32), 256, 0, stream>>>(qg, qWih, 512, qBih, qBhh, nullptr, nullptr, base);
    gate_kernel<<<4096, 256, 0, stream>>>(base, qg, cb, hb);   // step 1 (h_r = 0)
    for (int s = 0; s < 3; s++){
        gemm_mfma<<<dim3(32,32), 256, 0, stream>>>(hb, qWhh, 1024, nullptr, nullptr, base, wv, G);
        gate_kernel<<<4096, 256, 0, stream>>>(G, qg, cb, hb);
    }

    // matching_scores
    scores_kernel<<<512, 256, 0, stream>>>(hb, sgee, out);
}

// Round 4
// 848.185 us; speedup vs baseline: 2.2859x; 1.1574x over previous
//
#include <hip/hip_runtime.h>
#include <hip/hip_bf16.h>

#define NB 30
typedef unsigned short u16;

typedef __attribute__((ext_vector_type(8))) short bf16x8;
typedef __attribute__((ext_vector_type(4))) float f32x4;
#define MFMA16(a,b,c) __builtin_amdgcn_mfma_f32_16x16x32_bf16(a,b,c,0,0,0)

__device__ __forceinline__ float sigf(float x){ return 1.0f/(1.0f + __expf(-x)); }
__device__ __forceinline__ float ftanh(float x){
    float ax = fabsf(x);
    float e = __expf(-2.f*ax);
    float r = (1.f - e) / (1.f + e);
    return copysignf(r, x);
}
__device__ __forceinline__ u16 f2b(float f){
    unsigned u = __float_as_uint(f);
    u += 0x7fffu + ((u >> 16) & 1u);
    return (u16)(u >> 16);
}
__device__ __forceinline__ unsigned int pk2(float x, float y){
    return ((unsigned)f2b(y) << 16) | (unsigned)f2b(x);
}
__device__ __forceinline__ float b2f(u16 u){
    return __uint_as_float(((unsigned int)u) << 16);
}

// ---------------------------------------------------------------------------
// cvt_all: f32->bf16 for p1W (524288), p2W (524288), naW (131072)
// ---------------------------------------------------------------------------
__global__ __launch_bounds__(256) void cvt_all(
    const float* __restrict__ p1W, const float* __restrict__ p2W,
    const float* __restrict__ naW,
    u16* __restrict__ p1Wb, u16* __restrict__ p2Wb, u16* __restrict__ naWb)
{
    int gid = (blockIdx.x * 256 + threadIdx.x) * 4;
    const float* src; u16* dst; int off;
    if (gid < 524288){ src = p1W; dst = p1Wb; off = gid; }
    else if (gid < 1048576){ src = p2W; dst = p2Wb; off = gid - 524288; }
    else { src = naW; dst = naWb; off = gid - 1048576; }
    float4 v = *reinterpret_cast<const float4*>(src + off);
    uint2 s; s.x = pk2(v.x, v.y); s.y = pk2(v.z, v.w);
    *reinterpret_cast<uint2*>(dst + off) = s;
}

// ---------------------------------------------------------------------------
// pack live rows of qWih / qWhh(h-part) into bf16 [2048x512], n' = 4d+gate
// src row = (n'&3)*1024 + (n'>>2)
// ---------------------------------------------------------------------------
__global__ __launch_bounds__(256) void pack_sel(
    const float* __restrict__ src, int ld, u16* __restrict__ dst)
{
    const int t = threadIdx.x;
    const int n = blockIdx.x * 4 + (t >> 6);
    const int lane = t & 63;
    const int srow = (n & 3) * 1024 + (n >> 2);
    const float* sp = src + (size_t)srow * ld + lane * 8;
    float4 a = *reinterpret_cast<const float4*>(sp);
    float4 b = *reinterpret_cast<const float4*>(sp + 4);
    uint4 o;
    o.x = pk2(a.x, a.y); o.y = pk2(a.z, a.w);
    o.z = pk2(b.x, b.y); o.w = pk2(b.z, b.w);
    *reinterpret_cast<uint4*>(dst + (size_t)n * 512 + lane * 8) = o;
}

__global__ __launch_bounds__(256) void bias_comb_kernel(
    const float* __restrict__ qBih, const float* __restrict__ qBhh,
    float* __restrict__ bc)
{
    int n = blockIdx.x * 256 + threadIdx.x;
    int row = (n & 3) * 1024 + (n >> 2);
    bc[n] = qBih[row] + qBhh[row];
}

// ---------------------------------------------------------------------------
// Neighbor encoder (MFMA). One block per (row, side). Writes f32 + bf16.
// ---------------------------------------------------------------------------
#define CATP 520
__global__ __launch_bounds__(256) void neighbor_mfma(
    const int* __restrict__ connL, const int* __restrict__ connR,
    const float* __restrict__ emb, const u16* __restrict__ naWbf,
    const float* __restrict__ naB, const float* __restrict__ nuW,
    const float* __restrict__ nuB, float* __restrict__ out,
    u16* __restrict__ out_bf)
{
    __shared__ __align__(16) u16 cat[32][CATP];
    __shared__ float logit[32];
    __shared__ float att[NB];
    __shared__ int ids[NB*2];

    const int t = threadIdx.x;
    const int row = blockIdx.x, side = blockIdx.y;
    const int* conn = (side ? connR : connL) + (size_t)row * (NB*2);

    if (t < NB*2) ids[t] = conn[t];
    if (t >= 64 && t < 96) logit[t - 64] = 0.f;
    __syncthreads();

    for (int i = t; i < NB*128; i += 256){
        int k = i >> 7, e0 = (i & 127) * 4;
        int id  = (e0 < 256) ? ids[k*2] : ids[k*2+1];
        float4 v = *reinterpret_cast<const float4*>(emb + (size_t)id*256 + (e0 & 255));
        uint2 s; s.x = pk2(v.x, v.y); s.y = pk2(v.z, v.w);
        *reinterpret_cast<uint2*>(&cat[k][e0]) = s;
    }
    for (int i = t; i < 2*128; i += 256){
        int k = 30 + (i >> 7), e0 = (i & 127) * 4;
        uint2 z; z.x = 0u; z.y = 0u;
        *reinterpret_cast<uint2*>(&cat[k][e0]) = z;
    }
    __syncthreads();

    const int w = t >> 6, lane = t & 63;
    const int col = lane & 15, quad = lane >> 4;

    f32x4 acc[2][4] = {};
    for (int ks = 0; ks < 16; ks++){
        const int k0 = ks*32 + quad*8;
        bf16x8 a0 = *reinterpret_cast<const bf16x8*>(&cat[col][k0]);
        bf16x8 a1 = *reinterpret_cast<const bf16x8*>(&cat[16 + col][k0]);
        #pragma unroll
        for (int i = 0; i < 4; i++){
            int n = (w*4 + i)*16 + col;
            bf16x8 b = *reinterpret_cast<const bf16x8*>(naWbf + (size_t)n*512 + k0);
            acc[0][i] = MFMA16(a0, b, acc[0][i]);
            acc[1][i] = MFMA16(a1, b, acc[1][i]);
        }
    }

    float nu[4], nbv[4];
    #pragma unroll
    for (int i = 0; i < 4; i++){
        int n = (w*4 + i)*16 + col;
        nu[i] = nuW[n]; nbv[i] = naB[n];
    }
    #pragma unroll
    for (int mt = 0; mt < 2; mt++){
        #pragma unroll
        for (int r = 0; r < 4; r++){
            int m = mt*16 + quad*4 + r;
            float v = 0.f;
            #pragma unroll
            for (int i = 0; i < 4; i++)
                v += ftanh(acc[mt][i][r] + nbv[i]) * nu[i];
            v += __shfl_xor(v, 1); v += __shfl_xor(v, 2);
            v += __shfl_xor(v, 4); v += __shfl_xor(v, 8);
            if (col == 0 && m < NB) atomicAdd(&logit[m], v);
        }
    }
    __syncthreads();

    if (t == 0){
        const float nub = nuB[0];
        float mx = -1e30f;
        for (int k = 0; k < NB; k++){
            float L = logit[k] + nub;
            logit[k] = L; mx = fmaxf(mx, L);
        }
        float s = 0.f;
        for (int k = 0; k < NB; k++){ float e = __expf(logit[k] - mx); att[k] = e; s += e; }
        float inv = 1.f / s;
        for (int k = 0; k < NB; k++) att[k] *= inv;
    }
    __syncthreads();

    float agg = 0.f;
    #pragma unroll
    for (int k = 0; k < NB; k++) agg += att[k] * b2f(cat[k][256 + t]);
    float r = ftanh(agg);
    size_t oi = (size_t)row*512 + side*256 + t;
    out[oi] = r;
    out_bf[oi] = f2b(r);
}

// ---------------------------------------------------------------------------
// gemm128: C[m,n] = act( A[m,:]·B[n,:] + bias[n] (+addD[m,n]) )
// A bf16 [M x lda], B bf16 [N x ldb]. 128x128 tile, 4 waves of 64x64.
// ---------------------------------------------------------------------------
__global__ __launch_bounds__(256) void gemm128(
    const u16* __restrict__ A, int lda,
    const u16* __restrict__ B, int ldb,
    const float* __restrict__ bias,
    const float* __restrict__ addD, int ldd,
    float* __restrict__ Cf, u16* __restrict__ Cbf, int ldc,
    int K, int relu)
{
    __shared__ __align__(16) u16 As[128][72];
    __shared__ __align__(16) u16 Bs[128][72];
    const int t = threadIdx.x;
    const int m0 = blockIdx.y * 128, n0 = blockIdx.x * 128;
    const int w = t >> 6, lane = t & 63;
    const int col = lane & 15, quad = lane >> 4;
    const int wm = (w & 1) * 64, wn = (w >> 1) * 64;

    const int srow = t >> 1, sseg = t & 1;
    const u16* Ap = A + (size_t)(m0 + srow) * lda + sseg * 32;
    const u16* Bp = B + (size_t)(n0 + srow) * ldb + sseg * 32;

    f32x4 acc[4][4] = {};

    const int KC = K >> 6;
    for (int kc = 0; kc < KC; kc++){
        uint4 av[4], bv[4];
        #pragma unroll
        for (int j = 0; j < 4; j++){
            av[j] = *reinterpret_cast<const uint4*>(Ap + kc*64 + j*8);
            bv[j] = *reinterpret_cast<const uint4*>(Bp + kc*64 + j*8);
        }
        __syncthreads();
        #pragma unroll
        for (int j = 0; j < 4; j++){
            *reinterpret_cast<uint4*>(&As[srow][sseg*32 + j*8]) = av[j];
            *reinterpret_cast<uint4*>(&Bs[srow][sseg*32 + j*8]) = bv[j];
        }
        __syncthreads();
        #pragma unroll
        for (int ks = 0; ks < 2; ks++){
            const int k0 = ks*32 + quad*8;
            bf16x8 af[4], bf[4];
            #pragma unroll
            for (int i = 0; i < 4; i++) af[i] = *reinterpret_cast<const bf16x8*>(&As[wm + i*16 + col][k0]);
            #pragma unroll
            for (int j = 0; j < 4; j++) bf[j] = *reinterpret_cast<const bf16x8*>(&Bs[wn + j*16 + col][k0]);
            #pragma unroll
            for (int i = 0; i < 4; i++)
                #pragma unroll
                for (int j = 0; j < 4; j++)
                    acc[i][j] = MFMA16(af[i], bf[j], acc[i][j]);
        }
    }

    #pragma unroll
    for (int j = 0; j < 4; j++){
        int n = n0 + wn + j*16 + col;
        float bj = bias[n];
        #pragma unroll
        for (int i = 0; i < 4; i++){
            #pragma unroll
            for (int r = 0; r < 4; r++){
                int m = m0 + wm + i*16 + quad*4 + r;
                float v = acc[i][j][r] + bj;
                if (addD) v += addD[(size_t)m*ldd + n];
                if (relu) v = fmaxf(v, 0.f);
                if (Cf)  Cf[(size_t)m*ldc + n] = v;
                if (Cbf) Cbf[(size_t)m*ldc + n] = f2b(v);
            }
        }
    }
}

// ---------------------------------------------------------------------------
// LayerNorm(Z + X) with ddof=1, eps on sigma. One wave per row.
// ---------------------------------------------------------------------------
__global__ __launch_bounds__(256) void ln_kernel(
    const float* __restrict__ Z, const float* __restrict__ X, int N,
    const float* __restrict__ lnA, const float* __restrict__ lnB,
    float* __restrict__ Y, u16* __restrict__ Ybf, float* __restrict__ Ycopy)
{
    const int wv = threadIdx.x >> 6, lane = threadIdx.x & 63;
    const int row = blockIdx.x * 4 + wv;
    if (row >= N) return;
    const float* z = Z + (size_t)row * 512;
    const float* x = X + (size_t)row * 512;
    float v[8];
    float s = 0.f, ss = 0.f;
    {
        float4 z0 = *reinterpret_cast<const float4*>(z + lane*8);
        float4 z1 = *reinterpret_cast<const float4*>(z + lane*8 + 4);
        float4 x0 = *reinterpret_cast<const float4*>(x + lane*8);
        float4 x1 = *reinterpret_cast<const float4*>(x + lane*8 + 4);
        v[0]=z0.x+x0.x; v[1]=z0.y+x0.y; v[2]=z0.z+x0.z; v[3]=z0.w+x0.w;
        v[4]=z1.x+x1.x; v[5]=z1.y+x1.y; v[6]=z1.z+x1.z; v[7]=z1.w+x1.w;
    }
    #pragma unroll
    for (int u = 0; u < 8; u++){ s += v[u]; ss += v[u]*v[u]; }
    #pragma unroll
    for (int d = 1; d < 64; d <<= 1){
        s  += __shfl_xor(s, d);
        ss += __shfl_xor(ss, d);
    }
    float mu  = s * (1.f/512.f);
    float var = (ss - 512.f*mu*mu) * (1.f/511.f);
    float sd  = sqrtf(fmaxf(var, 0.f));
    float inv = 1.f / (sd + 1e-3f);
    float o[8];
    #pragma unroll
    for (int u = 0; u < 8; u++){
        int e = lane*8 + u;
        o[u] = (v[u] - mu) * inv * lnA[e] + lnB[e];
    }
    float* yr = Y + (size_t)row*512 + lane*8;
    *reinterpret_cast<float4*>(yr)     = make_float4(o[0],o[1],o[2],o[3]);
    *reinterpret_cast<float4*>(yr + 4) = make_float4(o[4],o[5],o[6],o[7]);
    if (Ybf){
        uint4 p;
        p.x = pk2(o[0],o[1]); p.y = pk2(o[2],o[3]);
        p.z = pk2(o[4],o[5]); p.w = pk2(o[6],o[7]);
        *reinterpret_cast<uint4*>(Ybf + (size_t)row*512 + lane*8) = p;
    }
    if (Ycopy){
        float* cr = Ycopy + (size_t)row*512 + lane*8;
        *reinterpret_cast<float4*>(cr)     = make_float4(o[0],o[1],o[2],o[3]);
        *reinterpret_cast<float4*>(cr + 4) = make_float4(o[4],o[5],o[6],o[7]);
    }
}

// ---------------------------------------------------------------------------
// Small LSTM cell (D=512, batch=1): 64 blocks x 8 d's
// ---------------------------------------------------------------------------
__global__ __launch_bounds__(256) void lstm_small(
    const float* __restrict__ x, const float* __restrict__ hin,
    float* __restrict__ c,
    const float* __restrict__ Wih, const float* __restrict__ Whh,
    const float* __restrict__ bih, const float* __restrict__ bhh,
    float* __restrict__ hout)
{
    __shared__ float xs[512], hs[512];
    __shared__ float gbuf[32];
    const int t = threadIdx.x;
    for (int i = t; i < 512; i += 256){ xs[i] = x[i]; hs[i] = hin[i]; }
    __syncthreads();

    const int dot = t >> 3, part = t & 7;   // 32 dots x 8 parts
    const int gate = dot >> 3, dl = dot & 7;
    const int d = blockIdx.x * 8 + dl;
    const int j = gate * 512 + d;
    const float4* wi = reinterpret_cast<const float4*>(Wih + (size_t)j*512) + part*16;
    const float4* wh = reinterpret_cast<const float4*>(Whh + (size_t)j*512) + part*16;
    float acc = 0.f;
    for (int kc = 0; kc < 16; kc++){
        float4 w = wi[kc];
        const int kb = part*64 + kc*4;
        acc += xs[kb]*w.x + xs[kb+1]*w.y + xs[kb+2]*w.z + xs[kb+3]*w.w;
        float4 v2 = wh[kc];
        acc += hs[kb]*v2.x + hs[kb+1]*v2.y + hs[kb+2]*v2.z + hs[kb+3]*v2.w;
    }
    acc += __shfl_xor(acc, 1);
    acc += __shfl_xor(acc, 2);
    acc += __shfl_xor(acc, 4);
    if (part == 0) gbuf[dot] = acc + bih[j] + bhh[j];
    __syncthreads();
    if (t < 8){
        int dd = blockIdx.x * 8 + t;
        float iv = gbuf[t], fv = gbuf[8+t], gv = gbuf[16+t], ov = gbuf[24+t];
        float cn = sigf(fv)*c[dd] + sigf(iv)*ftanh(gv);
        float hn = sigf(ov)*ftanh(cn);
        c[dd] = cn; hout[dd] = hn;
    }
}

// ---------------------------------------------------------------------------
// ae_loss + sge_enc (singleton softmax == 1)
// ---------------------------------------------------------------------------
__global__ __launch_bounds__(256) void finalize_kernel(
    const float* __restrict__ sg, const float* __restrict__ enc,
    const float* __restrict__ dec, float* __restrict__ sgeenc,
    float* __restrict__ outp)
{
    __shared__ float red[4];
    const int t = threadIdx.x;
    float s = 0.f;
    for (int i = t; i < 1536; i += 256){ float d = sg[i] - dec[i]; s += d*d; }
    s += __shfl_xor(s,1); s += __shfl_xor(s,2); s += __shfl_xor(s,4);
    s += __shfl_xor(s,8); s += __shfl_xor(s,16); s += __shfl_xor(s,32);
    if ((t & 63) == 0) red[t>>6] = s;
    __syncthreads();
    if (t == 0){
        float tot = (red[0]+red[1]+red[2]+red[3]) * (1.f/1536.f);
        outp[2048] = tot;
    }
    for (int d = t; d < 512; d += 256){
        float v = sg[d] + enc[d] + sg[512+d] + enc[512+d] + sg[1024+d] + enc[1024+d];
        sgeenc[d] = v;
        outp[2049 + d] = v;
    }
}

// ---------------------------------------------------------------------------
// wvec[n'] = sum_j sge[j] * qWhh[(n'&3)*1024 + (n'>>2), 512+j]  (packed order)
// ---------------------------------------------------------------------------
__global__ __launch_bounds__(256) void wvec_kernel(
    const float* __restrict__ qWhh, const float* __restrict__ sge,
    float* __restrict__ wvec)
{
    __shared__ float ss[512];
    const int t = threadIdx.x;
    for (int i = t; i < 512; i += 256) ss[i] = sge[i];
    __syncthreads();
    const int n = blockIdx.x * 256 + t;
    const int row = (n & 3) * 1024 + (n >> 2);
    const float4* w = reinterpret_cast<const float4*>(qWhh + (size_t)row*1024 + 512);
    float acc = 0.f;
    for (int kc = 0; kc < 128; kc++){
        float4 wv = w[kc];
        const int kb = kc*4;
        acc += ss[kb]*wv.x + ss[kb+1]*wv.y + ss[kb+2]*wv.z + ss[kb+3]*wv.w;
    }
    wvec[n] = acc;
}

// ---------------------------------------------------------------------------
// Gate math on packed G: g4 = (i,f,g,o) at G[b*2048 + 4d]
// ---------------------------------------------------------------------------
__global__ __launch_bounds__(256) void gate_kernel(
    const float* __restrict__ G, const float* __restrict__ qg,
    float* __restrict__ c, u16* __restrict__ h_bf)
{
    const int idx = blockIdx.x * 256 + threadIdx.x;
    const int b = idx >> 9, d = idx & 511;
    float4 g4 = *reinterpret_cast<const float4*>(G + (size_t)b*2048 + d*4);
    float cn = sigf(g4.y)*c[idx] + sigf(g4.x)*ftanh(g4.z);
    float hn = qg[idx] + sigf(g4.w)*ftanh(cn);
    c[idx] = cn; h_bf[idx] = f2b(hn);
}

// ---------------------------------------------------------------------------
// matching_scores[b] = dot(h[b], sge_enc)
// ---------------------------------------------------------------------------
__global__ __launch_bounds__(256) void scores_kernel(
    const u16* __restrict__ h, const float* __restrict__ sge,
    float* __restrict__ out)
{
    const int wave = threadIdx.x >> 6, lane = threadIdx.x & 63;
    const int row = blockIdx.x * 4 + wave;
    const u16* hr = h + (size_t)row * 512;
    float s = 0.f;
    for (int i = lane; i < 512; i += 64) s += b2f(hr[i]) * sge[i];
    s += __shfl_xor(s,1); s += __shfl_xor(s,2); s += __shfl_xor(s,4);
    s += __shfl_xor(s,8); s += __shfl_xor(s,16); s += __shfl_xor(s,32);
    if (lane == 0) out[row] = s;
}

// ---------------------------------------------------------------------------
extern "C" void kernel_launch(void* const* d_in, const int* in_sizes, int n_in,
                              void* d_out, int out_size, void* d_ws, size_t ws_size,
                              hipStream_t stream)
{
    (void)in_sizes; (void)n_in; (void)out_size; (void)ws_size;

    const int* qlc = (const int*)d_in[2];
    const int* qrc = (const int*)d_in[4];
    const int* slc = (const int*)d_in[6];
    const int* src = (const int*)d_in[8];
    const float* emb = (const float*)d_in[10];
    const float* naW = (const float*)d_in[11];
    const float* naB = (const float*)d_in[12];
    const float* nuW = (const float*)d_in[13];
    const float* nuB = (const float*)d_in[14];
    const float* p1W = (const float*)d_in[15], *p1b = (const float*)d_in[16];
    const float* p2W = (const float*)d_in[17], *p2b = (const float*)d_in[18];
    const float* lnA = (const float*)d_in[19], *lnB = (const float*)d_in[20];
    const float* eWih = (const float*)d_in[21], *eWhh = (const float*)d_in[22];
    const float* eBih = (const float*)d_in[23], *eBhh = (const float*)d_in[24];
    const float* dWih = (const float*)d_in[25], *dWhh = (const float*)d_in[26];
    const float* dBih = (const float*)d_in[27], *dBhh = (const float*)d_in[28];
    const float* qWih = (const float*)d_in[33], *qWhh = (const float*)d_in[34];
    const float* qBih = (const float*)d_in[35], *qBhh = (const float*)d_in[36];
    float* out = (float*)d_out;

    float* w = (float*)d_ws;
    size_t off = 0;
    auto alloc = [&](size_t nelem){ float* p = w + off; off += nelem; return p; };
    float* qn    = alloc(2048ull*512);   // query neighbor f32
    float* qg    = alloc(2048ull*512);   // query_g f32
    float* sn    = alloc(1536);
    float* sg    = alloc(1536);
    float* enc   = alloc(1536);
    float* dec   = alloc(1536);
    float* zc    = alloc(1024);          // zero h (512) + c_state (512)
    float* sgee  = alloc(512);
    float* wv    = alloc(2048);          // packed
    float* bc    = alloc(2048);          // bias_comb packed
    float* naWbF = alloc(65536);         // naW bf16
    float* base  = alloc(2048ull*2048);  // also: Zq @ [0,1M), qn_bf @ [1M,1.5M)
    float* G     = alloc(2048ull*2048);  // also: Hq_bf @ [0,1M), qg_bf @ [1M,1.5M)
    float* cb    = alloc(2048ull*512);   // c state
    float* hbfF  = alloc(2048ull*512/2); // h bf16 (0.5M f32 slots)
    float* p1WbF = alloc(262144);        // 524288 u16
    float* p2WbF = alloc(262144);
    float* WihSF = alloc(524288);        // 2048x512 u16 = 0.5M f32
    float* WhhSF = alloc(524288);
    float* snbfF = alloc(32768);         // 128x512 u16
    float* HsbfF = alloc(65536);         // 128x1024 u16
    float* Zs    = alloc(65536);         // 128x512 f32

    u16* naWb   = (u16*)naWbF;
    u16* p1Wb   = (u16*)p1WbF;
    u16* p2Wb   = (u16*)p2WbF;
    u16* WihSel = (u16*)WihSF;
    u16* WhhSel = (u16*)WhhSF;
    u16* sn_bf  = (u16*)snbfF;
    u16* Hs_bf  = (u16*)HsbfF;
    u16* h_bf   = (u16*)hbfF;
    float* Zq   = base;                       // [0, 1M) of base
    u16* qn_bf  = (u16*)(base + 1048576);     // [1M, 1.5M) of base
    u16* Hq_bf  = (u16*)G;                    // [0, 1M) of G
    u16* qg_bf  = (u16*)(G + 1048576);        // [1M, 1.5M) of G
    float* zbuf = zc;
    float* cst  = zc + 512;

    hipMemsetAsync(zc, 0, 1024*sizeof(float), stream);
    hipMemsetAsync(cb, 0, 2048ull*512*sizeof(float), stream);

    // weight preprocessing
    cvt_all<<<1152, 256, 0, stream>>>(p1W, p2W, naW, p1Wb, p2Wb, naWb);
    pack_sel<<<512, 256, 0, stream>>>(qWih, 512, WihSel);
    pack_sel<<<512, 256, 0, stream>>>(qWhh, 1024, WhhSel);
    bias_comb_kernel<<<8, 256, 0, stream>>>(qBih, qBhh, bc);

    // neighbor encoders
    neighbor_mfma<<<dim3(2048,2), 256, 0, stream>>>(qlc, qrc, emb, naWb, naB, nuW, nuB, qn, qn_bf);
    neighbor_mfma<<<dim3(3,2),    256, 0, stream>>>(slc, src, emb, naWb, naB, nuW, nuB, sn, sn_bf);

    // support encoder: H = relu(X@p1W^T+b); Z = H@p2W^T+b; LN(Z+X)
    gemm128<<<dim3(8,16), 256, 0, stream>>>(qn_bf, 512, p1Wb, 512, p1b, nullptr, 0,
                                            nullptr, Hq_bf, 1024, 512, 1);
    gemm128<<<dim3(8,1),  256, 0, stream>>>(sn_bf, 512, p1Wb, 512, p1b, nullptr, 0,
                                            nullptr, Hs_bf, 1024, 512, 1);
    gemm128<<<dim3(4,16), 256, 0, stream>>>(Hq_bf, 1024, p2Wb, 1024, p2b, nullptr, 0,
                                            Zq, nullptr, 512, 1024, 0);
    gemm128<<<dim3(4,1),  256, 0, stream>>>(Hs_bf, 1024, p2Wb, 1024, p2b, nullptr, 0,
                                            Zs, nullptr, 512, 1024, 0);
    ln_kernel<<<512, 256, 0, stream>>>(Zq, qn, 2048, lnA, lnB, qg, qg_bf, out + 2561);
    ln_kernel<<<1,   256, 0, stream>>>(Zs, sn, 3,    lnA, lnB, sg, nullptr, nullptr);

    // set autoencoder
    lstm_small<<<64, 256, 0, stream>>>(sg,        zbuf,      cst, eWih, eWhh, eBih, eBhh, enc);
    lstm_small<<<64, 256, 0, stream>>>(sg + 512,  enc,       cst, eWih, eWhh, eBih, eBhh, enc + 512);
    lstm_small<<<64, 256, 0, stream>>>(sg + 1024, enc + 512, cst, eWih, eWhh, eBih, eBhh, enc + 1024);
    lstm_small<<<64, 256, 0, stream>>>(enc + 1024, enc + 1024, cst, dWih, dWhh, dBih, dBhh, dec);
    lstm_small<<<64, 256, 0, stream>>>(dec,        dec,        cst, dWih, dWhh, dBih, dBhh, dec + 512);
    lstm_small<<<64, 256, 0, stream>>>(dec + 512,  dec + 512,  cst, dWih, dWhh, dBih, dBhh, dec + 1024);

    finalize_kernel<<<1, 256, 0, stream>>>(sg, enc, dec, sgee, out);
    wvec_kernel<<<8, 256, 0, stream>>>(qWhh, sgee, wv);

    // query encoder: base = qg@WihSel^T + bc; 4 steps
    gemm128<<<dim3(16,16), 256, 0, stream>>>(qg_bf, 512, WihSel, 512, bc, nullptr, 0,
                                             base, nullptr, 2048, 512, 0);
    gate_kernel<<<4096, 256, 0, stream>>>(base, qg, cb, h_bf);
    for (int s = 0; s < 3; s++){
        gemm128<<<dim3(16,16), 256, 0, stream>>>(h_bf, 512, WhhSel, 512, wv, base, 2048,
                                                 G, nullptr, 2048, 512, 0);
        gate_kernel<<<4096, 256, 0, stream>>>(G, qg, cb, h_bf);
    }

    scores_kernel<<<512, 256, 0, stream>>>(h_bf, sgee, out);
}

// Round 5
// 718.350 us; speedup vs baseline: 2.6991x; 1.1807x over previous
//
#include <hip/hip_runtime.h>
#include <hip/hip_bf16.h>

typedef unsigned short u16;
typedef __attribute__((ext_vector_type(8))) short bf16x8;
typedef __attribute__((ext_vector_type(4))) float f32x4;
#define MFMA16(a,b,c) __builtin_amdgcn_mfma_f32_16x16x32_bf16(a,b,c,0,0,0)
#define VPAD 100000

__device__ __forceinline__ float sigf(float x){ return 1.0f/(1.0f + __expf(-x)); }
__device__ __forceinline__ float ftanh(float x){
    float ax = fabsf(x);
    float e = __expf(-2.f*ax);
    float r = (1.f - e) / (1.f + e);
    return copysignf(r, x);
}
__device__ __forceinline__ u16 f2b(float f){
    unsigned u = __float_as_uint(f);
    u += 0x7fffu + ((u >> 16) & 1u);
    return (u16)(u >> 16);
}
__device__ __forceinline__ unsigned int pk2(float x, float y){
    return ((unsigned)f2b(y) << 16) | (unsigned)f2b(x);
}
__device__ __forceinline__ float b2f(u16 u){
    return __uint_as_float(((unsigned int)u) << 16);
}
__device__ __forceinline__ bf16x8 packA(float4 x, float4 y){
    union { bf16x8 v; uint4 u; } r;
    r.u.x = pk2(x.x,x.y); r.u.y = pk2(x.z,x.w);
    r.u.z = pk2(y.x,y.y); r.u.w = pk2(y.z,y.w);
    return r.v;
}

// ---------------------------------------------------------------------------
// prep: all weight preprocessing in one kernel.
//  - emb f32 -> bf16 (optional)
//  - p1W/p2W f32 -> bf16
//  - qWih/qWhh live-row pack (n' = 4d+gate) -> bf16 [2048x512]
//  - naW -> fragment-ordered bf16 blob [ks(16)][ig(16)][lane(64)][8]
//  - bias combine
// ---------------------------------------------------------------------------
__global__ __launch_bounds__(256) void prep_kernel(
    const float* __restrict__ emb, const float* __restrict__ p1W,
    const float* __restrict__ p2W, const float* __restrict__ naW,
    const float* __restrict__ qWih, const float* __restrict__ qWhh,
    const float* __restrict__ qBih, const float* __restrict__ qBhh,
    u16* __restrict__ embbf, u16* __restrict__ p1Wb, u16* __restrict__ p2Wb,
    u16* __restrict__ nawf, u16* __restrict__ WihS, u16* __restrict__ WhhS,
    float* __restrict__ bc, int useBf)
{
    const long gid = (long)blockIdx.x * 256 + threadIdx.x;
    const long E0 = 6400064;        // emb float4 units (25600256/4)
    const long E1 = E0 + 131072;    // p1W
    const long E2 = E1 + 131072;    // p2W
    const long E3 = E2 + 131072;    // Wih pack (8 u16/thread)
    const long E4 = E3 + 131072;    // Whh pack
    const long E5 = E4 + 16384;     // naW frag pack
    const long E6 = E5 + 2048;      // bias comb
    if (gid < E0){
        if (!useBf) return;
        float4 v = reinterpret_cast<const float4*>(emb)[gid];
        uint2 s; s.x = pk2(v.x,v.y); s.y = pk2(v.z,v.w);
        reinterpret_cast<uint2*>(embbf)[gid] = s;
    } else if (gid < E1){
        long i = gid - E0;
        float4 v = reinterpret_cast<const float4*>(p1W)[i];
        uint2 s; s.x = pk2(v.x,v.y); s.y = pk2(v.z,v.w);
        reinterpret_cast<uint2*>(p1Wb)[i] = s;
    } else if (gid < E2){
        long i = gid - E1;
        float4 v = reinterpret_cast<const float4*>(p2W)[i];
        uint2 s; s.x = pk2(v.x,v.y); s.y = pk2(v.z,v.w);
        reinterpret_cast<uint2*>(p2Wb)[i] = s;
    } else if (gid < E3){
        long j = gid - E2;                 // 0..131071
        int n = (int)(j >> 6), c8 = (int)(j & 63);
        int srow = (n & 3) * 1024 + (n >> 2);
        const float* sp = qWih + (size_t)srow * 512 + c8 * 8;
        float4 a = *reinterpret_cast<const float4*>(sp);
        float4 b = *reinterpret_cast<const float4*>(sp + 4);
        uint4 o; o.x = pk2(a.x,a.y); o.y = pk2(a.z,a.w);
        o.z = pk2(b.x,b.y); o.w = pk2(b.z,b.w);
        *reinterpret_cast<uint4*>(WihS + (size_t)n*512 + c8*8) = o;
    } else if (gid < E4){
        long j = gid - E3;
        int n = (int)(j >> 6), c8 = (int)(j & 63);
        int srow = (n & 3) * 1024 + (n >> 2);
        const float* sp = qWhh + (size_t)srow * 1024 + c8 * 8;
        float4 a = *reinterpret_cast<const float4*>(sp);
        float4 b = *reinterpret_cast<const float4*>(sp + 4);
        uint4 o; o.x = pk2(a.x,a.y); o.y = pk2(a.z,a.w);
        o.z = pk2(b.x,b.y); o.w = pk2(b.z,b.w);
        *reinterpret_cast<uint4*>(WhhS + (size_t)n*512 + c8*8) = o;
    } else if (gid < E5){
        long j = gid - E4;                 // 0..16383
        int f = (int)(j >> 6), lane = (int)(j & 63);
        int ks = f >> 4, ig = f & 15;
        int col = lane & 15, quad = lane >> 4;
        int n = ig*16 + col;
        int k0 = ks*32 + quad*8;
        const float* sp = naW + (size_t)n*512 + k0;
        float4 a = *reinterpret_cast<const float4*>(sp);
        float4 b = *reinterpret_cast<const float4*>(sp + 4);
        uint4 o; o.x = pk2(a.x,a.y); o.y = pk2(a.z,a.w);
        o.z = pk2(b.x,b.y); o.w = pk2(b.z,b.w);
        *reinterpret_cast<uint4*>(nawf + j*8) = o;
    } else if (gid < E6){
        int n = (int)(gid - E5);
        int row = (n & 3) * 1024 + (n >> 2);
        bc[n] = qBih[row] + qBhh[row];
    }
}

// ---------------------------------------------------------------------------
// Neighbor encoder v3: one block per logical row (0..2050), both sides.
// A-fragments gathered straight from emb (bf16) into registers; B streamed
// from fragment-packed naW (coalesced 1KB/wave) and reused by both sides.
// ---------------------------------------------------------------------------
__global__ __launch_bounds__(256) void neighbor_v3(
    const int* __restrict__ qL, const int* __restrict__ qR,
    const int* __restrict__ sL, const int* __restrict__ sR,
    const float* __restrict__ embf, const u16* __restrict__ embb, int useBf,
    const u16* __restrict__ nawf,
    const float* __restrict__ naB, const float* __restrict__ nuW,
    const float* __restrict__ nuB,
    float* __restrict__ out, u16* __restrict__ out_bf)
{
    __shared__ int relid[2][32];
    __shared__ int entid[2][32];
    __shared__ float logit[2][32];
    __shared__ float att[2][32];

    const int t = threadIdx.x;
    const int row = blockIdx.x;   // 0..2050
    if (t < 128){
        int s = t >> 6, j = t & 63;
        int k = j >> 1, which = j & 1;
        const int* conn;
        if (row < 2048) conn = (s ? qR : qL) + (size_t)row * 60;
        else            conn = (s ? sR : sL) + (size_t)(row - 2048) * 60;
        int id = (k < 30) ? conn[k*2 + which] : VPAD;
        if (which) entid[s][k] = id; else relid[s][k] = id;
    }
    if (t >= 128 && t < 192){ int s = (t-128) >> 5; logit[s][(t-128)&31] = 0.f; }
    __syncthreads();

    const int w = t >> 6, lane = t & 63;
    const int col = lane & 15, quad = lane >> 4;

    // u = s*2 + mt
    int ridv[4], eidv[4];
    #pragma unroll
    for (int u = 0; u < 4; u++){
        int s = u >> 1, mt = u & 1;
        int kn = mt*16 + col;
        ridv[u] = relid[s][kn];
        eidv[u] = entid[s][kn];
    }

    f32x4 acc[4][4] = {};

    if (useBf){
        const u16* baseR[4];
        const u16* baseE[4];
        #pragma unroll
        for (int u = 0; u < 4; u++){
            baseR[u] = embb + (size_t)ridv[u]*256 + quad*8;
            baseE[u] = embb + (size_t)eidv[u]*256 + quad*8;
        }
        #pragma unroll
        for (int ks = 0; ks < 16; ks++){
            const int off = (ks & 7) * 32;
            bf16x8 a[4], b[4];
            #pragma unroll
            for (int u = 0; u < 4; u++)
                a[u] = *reinterpret_cast<const bf16x8*>((ks < 8 ? baseR[u] : baseE[u]) + off);
            #pragma unroll
            for (int i = 0; i < 4; i++)
                b[i] = *reinterpret_cast<const bf16x8*>(nawf + ((size_t)(ks*16 + w*4 + i)*64 + lane)*8);
            #pragma unroll
            for (int i = 0; i < 4; i++)
                #pragma unroll
                for (int u = 0; u < 4; u++)
                    acc[u][i] = MFMA16(a[u], b[i], acc[u][i]);
        }
    } else {
        const float* baseR[4];
        const float* baseE[4];
        #pragma unroll
        for (int u = 0; u < 4; u++){
            baseR[u] = embf + (size_t)ridv[u]*256 + quad*8;
            baseE[u] = embf + (size_t)eidv[u]*256 + quad*8;
        }
        #pragma unroll
        for (int ks = 0; ks < 16; ks++){
            const int off = (ks & 7) * 32;
            bf16x8 a[4], b[4];
            #pragma unroll
            for (int u = 0; u < 4; u++){
                const float* p = (ks < 8 ? baseR[u] : baseE[u]) + off;
                float4 x = *reinterpret_cast<const float4*>(p);
                float4 y = *reinterpret_cast<const float4*>(p + 4);
                a[u] = packA(x, y);
            }
            #pragma unroll
            for (int i = 0; i < 4; i++)
                b[i] = *reinterpret_cast<const bf16x8*>(nawf + ((size_t)(ks*16 + w*4 + i)*64 + lane)*8);
            #pragma unroll
            for (int i = 0; i < 4; i++)
                #pragma unroll
                for (int u = 0; u < 4; u++)
                    acc[u][i] = MFMA16(a[u], b[i], acc[u][i]);
        }
    }

    // logits
    float nu[4], nbv[4];
    #pragma unroll
    for (int i = 0; i < 4; i++){
        int n = (w*4 + i)*16 + col;
        nu[i] = nuW[n]; nbv[i] = naB[n];
    }
    #pragma unroll
    for (int u = 0; u < 4; u++){
        int s = u >> 1, mt = u & 1;
        #pragma unroll
        for (int r = 0; r < 4; r++){
            int m = mt*16 + quad*4 + r;
            float v = 0.f;
            #pragma unroll
            for (int i = 0; i < 4; i++)
                v += ftanh(acc[u][i][r] + nbv[i]) * nu[i];
            v += __shfl_xor(v, 1); v += __shfl_xor(v, 2);
            v += __shfl_xor(v, 4); v += __shfl_xor(v, 8);
            if (col == 0 && m < 30) atomicAdd(&logit[s][m], v);
        }
    }
    __syncthreads();

    if (t < 2){
        const int s = t;
        const float nub = nuB[0];
        float mx = -1e30f;
        float lg[30];
        #pragma unroll
        for (int k = 0; k < 30; k++){
            float L = logit[s][k] + nub;
            lg[k] = L; mx = fmaxf(mx, L);
        }
        float sm = 0.f;
        #pragma unroll
        for (int k = 0; k < 30; k++){ float e = __expf(lg[k]-mx); att[s][k] = e; sm += e; }
        float inv = 1.f / sm;
        #pragma unroll
        for (int k = 0; k < 30; k++) att[s][k] *= inv;
    }
    __syncthreads();

    // agg: thread t = column e (0..255), both sides
    const int e = t;
    #pragma unroll
    for (int s = 0; s < 2; s++){
        float agg = 0.f;
        #pragma unroll
        for (int k = 0; k < 30; k++){
            int id = entid[s][k];
            float ev = useBf ? b2f(embb[(size_t)id*256 + e])
                             : embf[(size_t)id*256 + e];
            agg += att[s][k] * ev;
        }
        float r = ftanh(agg);
        size_t oi = (size_t)row*512 + s*256 + e;
        out[oi] = r;
        out_bf[oi] = f2b(r);
    }
}

// ---------------------------------------------------------------------------
// gemm128: C[m,n] = act( A[m,:]·B[n,:] + bias[n] (+addD[m,n]) )
// A bf16 [M x lda], B bf16 [N x ldb]. 128x128 tile, 4 waves of 64x64.
// ---------------------------------------------------------------------------
__global__ __launch_bounds__(256) void gemm128(
    const u16* __restrict__ A, int lda,
    const u16* __restrict__ B, int ldb,
    const float* __restrict__ bias,
    const float* __restrict__ addD, int ldd,
    float* __restrict__ Cf, u16* __restrict__ Cbf, int ldc,
    int K, int relu)
{
    __shared__ __align__(16) u16 As[128][72];
    __shared__ __align__(16) u16 Bs[128][72];
    const int t = threadIdx.x;
    const int m0 = blockIdx.y * 128, n0 = blockIdx.x * 128;
    const int w = t >> 6, lane = t & 63;
    const int col = lane & 15, quad = lane >> 4;
    const int wm = (w & 1) * 64, wn = (w >> 1) * 64;

    const int srow = t >> 1, sseg = t & 1;
    const u16* Ap = A + (size_t)(m0 + srow) * lda + sseg * 32;
    const u16* Bp = B + (size_t)(n0 + srow) * ldb + sseg * 32;

    f32x4 acc[4][4] = {};

    const int KC = K >> 6;
    for (int kc = 0; kc < KC; kc++){
        uint4 av[4], bv[4];
        #pragma unroll
        for (int j = 0; j < 4; j++){
            av[j] = *reinterpret_cast<const uint4*>(Ap + kc*64 + j*8);
            bv[j] = *reinterpret_cast<const uint4*>(Bp + kc*64 + j*8);
        }
        __syncthreads();
        #pragma unroll
        for (int j = 0; j < 4; j++){
            *reinterpret_cast<uint4*>(&As[srow][sseg*32 + j*8]) = av[j];
            *reinterpret_cast<uint4*>(&Bs[srow][sseg*32 + j*8]) = bv[j];
        }
        __syncthreads();
        #pragma unroll
        for (int ks = 0; ks < 2; ks++){
            const int k0 = ks*32 + quad*8;
            bf16x8 af[4], bf[4];
            #pragma unroll
            for (int i = 0; i < 4; i++) af[i] = *reinterpret_cast<const bf16x8*>(&As[wm + i*16 + col][k0]);
            #pragma unroll
            for (int j = 0; j < 4; j++) bf[j] = *reinterpret_cast<const bf16x8*>(&Bs[wn + j*16 + col][k0]);
            #pragma unroll
            for (int i = 0; i < 4; i++)
                #pragma unroll
                for (int j = 0; j < 4; j++)
                    acc[i][j] = MFMA16(af[i], bf[j], acc[i][j]);
        }
    }

    #pragma unroll
    for (int j = 0; j < 4; j++){
        int n = n0 + wn + j*16 + col;
        float bj = bias[n];
        #pragma unroll
        for (int i = 0; i < 4; i++){
            #pragma unroll
            for (int r = 0; r < 4; r++){
                int m = m0 + wm + i*16 + quad*4 + r;
                float v = acc[i][j][r] + bj;
                if (addD) v += addD[(size_t)m*ldd + n];
                if (relu) v = fmaxf(v, 0.f);
                if (Cf)  Cf[(size_t)m*ldc + n] = v;
                if (Cbf) Cbf[(size_t)m*ldc + n] = f2b(v);
            }
        }
    }
}

// ---------------------------------------------------------------------------
// LayerNorm(Z + X), ddof=1, eps on sigma. One wave per row; 2051 rows.
// ---------------------------------------------------------------------------
__global__ __launch_bounds__(256) void ln_kernel(
    const float* __restrict__ Z, const float* __restrict__ X, int N, int nquery,
    const float* __restrict__ lnA, const float* __restrict__ lnB,
    float* __restrict__ Y, u16* __restrict__ Ybf, float* __restrict__ Ycopy)
{
    const int wv = threadIdx.x >> 6, lane = threadIdx.x & 63;
    const int row = blockIdx.x * 4 + wv;
    if (row >= N) return;
    const float* z = Z + (size_t)row * 512;
    const float* x = X + (size_t)row * 512;
    float v[8];
    float s = 0.f, ss = 0.f;
    {
        float4 z0 = *reinterpret_cast<const float4*>(z + lane*8);
        float4 z1 = *reinterpret_cast<const float4*>(z + lane*8 + 4);
        float4 x0 = *reinterpret_cast<const float4*>(x + lane*8);
        float4 x1 = *reinterpret_cast<const float4*>(x + lane*8 + 4);
        v[0]=z0.x+x0.x; v[1]=z0.y+x0.y; v[2]=z0.z+x0.z; v[3]=z0.w+x0.w;
        v[4]=z1.x+x1.x; v[5]=z1.y+x1.y; v[6]=z1.z+x1.z; v[7]=z1.w+x1.w;
    }
    #pragma unroll
    for (int u = 0; u < 8; u++){ s += v[u]; ss += v[u]*v[u]; }
    #pragma unroll
    for (int d = 1; d < 64; d <<= 1){
        s  += __shfl_xor(s, d);
        ss += __shfl_xor(ss, d);
    }
    float mu  = s * (1.f/512.f);
    float var = (ss - 512.f*mu*mu) * (1.f/511.f);
    float sd  = sqrtf(fmaxf(var, 0.f));
    float inv = 1.f / (sd + 1e-3f);
    float o[8];
    #pragma unroll
    for (int u = 0; u < 8; u++){
        int e = lane*8 + u;
        o[u] = (v[u] - mu) * inv * lnA[e] + lnB[e];
    }
    float* yr = Y + (size_t)row*512 + lane*8;
    *reinterpret_cast<float4*>(yr)     = make_float4(o[0],o[1],o[2],o[3]);
    *reinterpret_cast<float4*>(yr + 4) = make_float4(o[4],o[5],o[6],o[7]);
    if (row < nquery){
        uint4 p;
        p.x = pk2(o[0],o[1]); p.y = pk2(o[2],o[3]);
        p.z = pk2(o[4],o[5]); p.w = pk2(o[6],o[7]);
        *reinterpret_cast<uint4*>(Ybf + (size_t)row*512 + lane*8) = p;
        float* cr = Ycopy + (size_t)row*512 + lane*8;
        *reinterpret_cast<float4*>(cr)     = make_float4(o[0],o[1],o[2],o[3]);
        *reinterpret_cast<float4*>(cr + 4) = make_float4(o[4],o[5],o[6],o[7]);
    }
}

// ---------------------------------------------------------------------------
// Small LSTM cell (D=512, batch=1): 128 blocks x 4 d, one wave per d
// ---------------------------------------------------------------------------
__global__ __launch_bounds__(256) void lstm_small(
    const float* __restrict__ x, const float* __restrict__ hin,
    float* __restrict__ c,
    const float* __restrict__ Wih, const float* __restrict__ Whh,
    const float* __restrict__ bih, const float* __restrict__ bhh,
    float* __restrict__ hout)
{
    __shared__ float xs[512], hs[512];
    __shared__ float gbuf[4][4];
    const int t = threadIdx.x;
    for (int i = t; i < 512; i += 256){ xs[i] = x[i]; hs[i] = hin[i]; }
    __syncthreads();

    const int wd = t >> 6;          // local d 0..3
    const int lane = t & 63;
    const int g = lane >> 4, p = lane & 15;
    const int d = blockIdx.x*4 + wd;
    const int j = g*512 + d;
    const float4* wi = reinterpret_cast<const float4*>(Wih + (size_t)j*512) + p*8;
    const float4* wh = reinterpret_cast<const float4*>(Whh + (size_t)j*512) + p*8;
    float acc = 0.f;
    #pragma unroll
    for (int q = 0; q < 8; q++){
        float4 wv = wi[q];
        const int kb = p*32 + q*4;
        acc += xs[kb]*wv.x + xs[kb+1]*wv.y + xs[kb+2]*wv.z + xs[kb+3]*wv.w;
        float4 vv = wh[q];
        acc += hs[kb]*vv.x + hs[kb+1]*vv.y + hs[kb+2]*vv.z + hs[kb+3]*vv.w;
    }
    acc += __shfl_xor(acc, 1); acc += __shfl_xor(acc, 2);
    acc += __shfl_xor(acc, 4); acc += __shfl_xor(acc, 8);
    if (p == 0) gbuf[wd][g] = acc + bih[j] + bhh[j];
    __syncthreads();
    if (t < 4){
        int dd = blockIdx.x*4 + t;
        float iv = gbuf[t][0], fv = gbuf[t][1], gv = gbuf[t][2], ov = gbuf[t][3];
        float cn = sigf(fv)*c[dd] + sigf(iv)*ftanh(gv);
        float hn = sigf(ov)*ftanh(cn);
        c[dd] = cn; hout[dd] = hn;
    }
}

// ---------------------------------------------------------------------------
// ae_loss + sge_enc (singleton softmax == 1)
// ---------------------------------------------------------------------------
__global__ __launch_bounds__(256) void finalize_kernel(
    const float* __restrict__ sg, const float* __restrict__ enc,
    const float* __restrict__ dec, float* __restrict__ sgeenc,
    float* __restrict__ outp)
{
    __shared__ float red[4];
    const int t = threadIdx.x;
    float s = 0.f;
    for (int i = t; i < 1536; i += 256){ float d = sg[i] - dec[i]; s += d*d; }
    s += __shfl_xor(s,1); s += __shfl_xor(s,2); s += __shfl_xor(s,4);
    s += __shfl_xor(s,8); s += __shfl_xor(s,16); s += __shfl_xor(s,32);
    if ((t & 63) == 0) red[t>>6] = s;
    __syncthreads();
    if (t == 0){
        float tot = (red[0]+red[1]+red[2]+red[3]) * (1.f/1536.f);
        outp[2048] = tot;
    }
    for (int d = t; d < 512; d += 256){
        float v = sg[d] + enc[d] + sg[512+d] + enc[512+d] + sg[1024+d] + enc[1024+d];
        sgeenc[d] = v;
        outp[2049 + d] = v;
    }
}

// ---------------------------------------------------------------------------
// wvec[n'] = sum_j sge[j] * qWhh[(n'&3)*1024 + (n'>>2), 512+j]
// ---------------------------------------------------------------------------
__global__ __launch_bounds__(256) void wvec_kernel(
    const float* __restrict__ qWhh, const float* __restrict__ sge,
    float* __restrict__ wvec)
{
    __shared__ float ss[512];
    const int t = threadIdx.x;
    for (int i = t; i < 512; i += 256) ss[i] = sge[i];
    __syncthreads();
    const int n = blockIdx.x * 256 + t;
    const int row = (n & 3) * 1024 + (n >> 2);
    const float4* w = reinterpret_cast<const float4*>(qWhh + (size_t)row*1024 + 512);
    float acc = 0.f;
    for (int kc = 0; kc < 128; kc++){
        float4 wv = w[kc];
        const int kb = kc*4;
        acc += ss[kb]*wv.x + ss[kb+1]*wv.y + ss[kb+2]*wv.z + ss[kb+3]*wv.w;
    }
    wvec[n] = acc;
}

// ---------------------------------------------------------------------------
// Gate math on packed G: g4 = (i,f,g,o) at G[b*2048 + 4d]
// ---------------------------------------------------------------------------
__global__ __launch_bounds__(256) void gate_kernel(
    const float* __restrict__ G, const float* __restrict__ qg,
    float* __restrict__ c, u16* __restrict__ h_bf)
{
    const int idx = blockIdx.x * 256 + threadIdx.x;
    const int b = idx >> 9, d = idx & 511;
    float4 g4 = *reinterpret_cast<const float4*>(G + (size_t)b*2048 + d*4);
    float cn = sigf(g4.y)*c[idx] + sigf(g4.x)*ftanh(g4.z);
    float hn = qg[idx] + sigf(g4.w)*ftanh(cn);
    c[idx] = cn; h_bf[idx] = f2b(hn);
}

// ---------------------------------------------------------------------------
// matching_scores[b] = dot(h[b], sge_enc)
// ---------------------------------------------------------------------------
__global__ __launch_bounds__(256) void scores_kernel(
    const u16* __restrict__ h, const float* __restrict__ sge,
    float* __restrict__ out)
{
    const int wave = threadIdx.x >> 6, lane = threadIdx.x & 63;
    const int row = blockIdx.x * 4 + wave;
    const u16* hr = h + (size_t)row * 512;
    float s = 0.f;
    for (int i = lane; i < 512; i += 64) s += b2f(hr[i]) * sge[i];
    s += __shfl_xor(s,1); s += __shfl_xor(s,2); s += __shfl_xor(s,4);
    s += __shfl_xor(s,8); s += __shfl_xor(s,16); s += __shfl_xor(s,32);
    if (lane == 0) out[row] = s;
}

// ---------------------------------------------------------------------------
extern "C" void kernel_launch(void* const* d_in, const int* in_sizes, int n_in,
                              void* d_out, int out_size, void* d_ws, size_t ws_size,
                              hipStream_t stream)
{
    (void)in_sizes; (void)n_in; (void)out_size;

    const int* qlc = (const int*)d_in[2];
    const int* qrc = (const int*)d_in[4];
    const int* slc = (const int*)d_in[6];
    const int* src = (const int*)d_in[8];
    const float* emb = (const float*)d_in[10];
    const float* naW = (const float*)d_in[11];
    const float* naB = (const float*)d_in[12];
    const float* nuW = (const float*)d_in[13];
    const float* nuB = (const float*)d_in[14];
    const float* p1W = (const float*)d_in[15], *p1b = (const float*)d_in[16];
    const float* p2W = (const float*)d_in[17], *p2b = (const float*)d_in[18];
    const float* lnA = (const float*)d_in[19], *lnB = (const float*)d_in[20];
    const float* eWih = (const float*)d_in[21], *eWhh = (const float*)d_in[22];
    const float* eBih = (const float*)d_in[23], *eBhh = (const float*)d_in[24];
    const float* dWih = (const float*)d_in[25], *dWhh = (const float*)d_in[26];
    const float* dBih = (const float*)d_in[27], *dBhh = (const float*)d_in[28];
    const float* qWih = (const float*)d_in[33], *qWhh = (const float*)d_in[34];
    const float* qBih = (const float*)d_in[35], *qBhh = (const float*)d_in[36];
    float* out = (float*)d_out;

    float* w = (float*)d_ws;
    size_t off = 0;
    auto alloc = [&](size_t nelem){ float* p = w + off; off += nelem; return p; };
    float* qn    = alloc(2176ull*512);   // neighbor f32 (2051 rows used)
    float* qg    = alloc(2176ull*512);   // query_g f32 (+ sg rows 2048..2050)
    float* enc   = alloc(1536);
    float* dec   = alloc(1536);
    float* zc    = alloc(1024);
    float* sgee  = alloc(512);
    float* wv    = alloc(2048);
    float* bc    = alloc(2048);
    float* nawfF = alloc(65536);         // 131072 u16 frag-packed naW
    float* base  = alloc(2048ull*2048);  // + Zq, qn_bf aliases
    float* G     = alloc(2048ull*2048);  // + Hq_bf, qg_bf aliases
    float* cb    = alloc(2048ull*512);
    float* hbfF  = alloc(524288);        // h bf16
    float* p1WbF = alloc(262144);
    float* p2WbF = alloc(262144);
    float* WihSF = alloc(524288);
    float* WhhSF = alloc(524288);
    size_t needNoEmb = off;
    float* embbF = alloc(12800128);      // emb bf16 (25,600,256 u16)
    size_t needEmb = off;
    int useBf = (ws_size >= needEmb * sizeof(float)) ? 1 : 0;
    (void)needNoEmb;

    u16* nawf   = (u16*)nawfF;
    u16* p1Wb   = (u16*)p1WbF;
    u16* p2Wb   = (u16*)p2WbF;
    u16* WihSel = (u16*)WihSF;
    u16* WhhSel = (u16*)WhhSF;
    u16* h_bf   = (u16*)hbfF;
    u16* embbf  = (u16*)embbF;
    float* Zq   = base;                       // 2176x512 f32
    u16* qn_bf  = (u16*)(base + 2097152);     // 2176x512 u16
    u16* Hq_bf  = (u16*)G;                    // 2176x1024 u16
    u16* qg_bf  = (u16*)(G + 2097152);        // 2176x512 u16 (2048 used)
    float* sg   = qg + 2048ull*512;
    float* zbuf = zc;
    float* cst  = zc + 512;

    hipMemsetAsync(zc, 0, 1024*sizeof(float), stream);
    hipMemsetAsync(cb, 0, 2048ull*512*sizeof(float), stream);

    // fused weight preprocessing
    prep_kernel<<<27121, 256, 0, stream>>>(emb, p1W, p2W, naW, qWih, qWhh, qBih, qBhh,
                                           embbf, p1Wb, p2Wb, nawf, WihSel, WhhSel,
                                           bc, useBf);

    // neighbor encoder: 2051 rows (2048 query + 3 support), both sides
    neighbor_v3<<<2051, 256, 0, stream>>>(qlc, qrc, slc, src, emb, embbf, useBf,
                                          nawf, naB, nuW, nuB, qn, qn_bf);

    // support encoder fused over 2051 rows: H=relu(X@p1W^T+b); Z=H@p2W^T+b; LN
    gemm128<<<dim3(8,17), 256, 0, stream>>>(qn_bf, 512, p1Wb, 512, p1b, nullptr, 0,
                                            nullptr, Hq_bf, 1024, 512, 1);
    gemm128<<<dim3(4,17), 256, 0, stream>>>(Hq_bf, 1024, p2Wb, 1024, p2b, nullptr, 0,
                                            Zq, nullptr, 512, 1024, 0);
    ln_kernel<<<513, 256, 0, stream>>>(Zq, qn, 2051, 2048, lnA, lnB, qg, qg_bf, out + 2561);

    // set autoencoder
    lstm_small<<<128, 256, 0, stream>>>(sg,        zbuf,      cst, eWih, eWhh, eBih, eBhh, enc);
    lstm_small<<<128, 256, 0, stream>>>(sg + 512,  enc,       cst, eWih, eWhh, eBih, eBhh, enc + 512);
    lstm_small<<<128, 256, 0, stream>>>(sg + 1024, enc + 512, cst, eWih, eWhh, eBih, eBhh, enc + 1024);
    lstm_small<<<128, 256, 0, stream>>>(enc + 1024, enc + 1024, cst, dWih, dWhh, dBih, dBhh, dec);
    lstm_small<<<128, 256, 0, stream>>>(dec,        dec,        cst, dWih, dWhh, dBih, dBhh, dec + 512);
    lstm_small<<<128, 256, 0, stream>>>(dec + 512,  dec + 512,  cst, dWih, dWhh, dBih, dBhh, dec + 1024);

    finalize_kernel<<<1, 256, 0, stream>>>(sg, enc, dec, sgee, out);
    wvec_kernel<<<8, 256, 0, stream>>>(qWhh, sgee, wv);

    // query encoder: base = qg@WihSel^T + bc; 4 steps (live half only)
    gemm128<<<dim3(16,16), 256, 0, stream>>>(qg_bf, 512, WihSel, 512, bc, nullptr, 0,
                                             base, nullptr, 2048, 512, 0);
    gate_kernel<<<4096, 256, 0, stream>>>(base, qg, cb, h_bf);
    for (int s = 0; s < 3; s++){
        gemm128<<<dim3(16,16), 256, 0, stream>>>(h_bf, 512, WhhSel, 512, wv, base, 2048,
                                                 G, nullptr, 2048, 512, 0);
        gate_kernel<<<4096, 256, 0, stream>>>(G, qg, cb, h_bf);
    }

    scores_kernel<<<512, 256, 0, stream>>>(h_bf, sgee, out);
}

// Round 6
// 633.913 us; speedup vs baseline: 3.0586x; 1.1332x over previous
//
#include <hip/hip_runtime.h>
#include <hip/hip_bf16.h>

typedef unsigned short u16;
typedef __attribute__((ext_vector_type(8))) short bf16x8;
typedef __attribute__((ext_vector_type(4))) float f32x4;
#define MFMA16(a,b,c) __builtin_amdgcn_mfma_f32_16x16x32_bf16(a,b,c,0,0,0)
#define VPAD 100000

__device__ __forceinline__ float sigf(float x){ return 1.0f/(1.0f + __expf(-x)); }
__device__ __forceinline__ float ftanh(float x){
    float ax = fabsf(x);
    float e = __expf(-2.f*ax);
    float r = (1.f - e) / (1.f + e);
    return copysignf(r, x);
}
__device__ __forceinline__ u16 f2b(float f){
    unsigned u = __float_as_uint(f);
    u += 0x7fffu + ((u >> 16) & 1u);
    return (u16)(u >> 16);
}
__device__ __forceinline__ unsigned int pk2(float x, float y){
    return ((unsigned)f2b(y) << 16) | (unsigned)f2b(x);
}
__device__ __forceinline__ float b2f(u16 u){
    return __uint_as_float(((unsigned int)u) << 16);
}
__device__ __forceinline__ uint4 pk8(float4 x, float4 y){
    uint4 o;
    o.x = pk2(x.x,x.y); o.y = pk2(x.z,x.w);
    o.z = pk2(y.x,y.y); o.w = pk2(y.z,y.w);
    return o;
}

// ---------------------------------------------------------------------------
// prep: weight preprocessing (no emb conversion anymore).
//  p1W/p2W f32->bf16; qWih/qWhh live-row pack (n'=4d+gate); naW frag blob;
//  bias combine.
// ---------------------------------------------------------------------------
__global__ __launch_bounds__(256) void prep_kernel(
    const float* __restrict__ p1W, const float* __restrict__ p2W,
    const float* __restrict__ naW,
    const float* __restrict__ qWih, const float* __restrict__ qWhh,
    const float* __restrict__ qBih, const float* __restrict__ qBhh,
    u16* __restrict__ p1Wb, u16* __restrict__ p2Wb,
    u16* __restrict__ nawf, u16* __restrict__ WihS, u16* __restrict__ WhhS,
    float* __restrict__ bc)
{
    const long gid = (long)blockIdx.x * 256 + threadIdx.x;
    const long E0 = 131072;         // p1W float4 units
    const long E1 = E0 + 131072;    // p2W
    const long E2 = E1 + 131072;    // Wih pack (8 u16/thread)
    const long E3 = E2 + 131072;    // Whh pack
    const long E4 = E3 + 16384;     // naW frag pack
    const long E5 = E4 + 2048;      // bias comb
    if (gid < E0){
        float4 v = reinterpret_cast<const float4*>(p1W)[gid];
        uint2 s; s.x = pk2(v.x,v.y); s.y = pk2(v.z,v.w);
        reinterpret_cast<uint2*>(p1Wb)[gid] = s;
    } else if (gid < E1){
        long i = gid - E0;
        float4 v = reinterpret_cast<const float4*>(p2W)[i];
        uint2 s; s.x = pk2(v.x,v.y); s.y = pk2(v.z,v.w);
        reinterpret_cast<uint2*>(p2Wb)[i] = s;
    } else if (gid < E2){
        long j = gid - E1;
        int n = (int)(j >> 6), c8 = (int)(j & 63);
        int srow = (n & 3) * 1024 + (n >> 2);
        const float* sp = qWih + (size_t)srow * 512 + c8 * 8;
        float4 a = *reinterpret_cast<const float4*>(sp);
        float4 b = *reinterpret_cast<const float4*>(sp + 4);
        *reinterpret_cast<uint4*>(WihS + (size_t)n*512 + c8*8) = pk8(a,b);
    } else if (gid < E3){
        long j = gid - E2;
        int n = (int)(j >> 6), c8 = (int)(j & 63);
        int srow = (n & 3) * 1024 + (n >> 2);
        const float* sp = qWhh + (size_t)srow * 1024 + c8 * 8;
        float4 a = *reinterpret_cast<const float4*>(sp);
        float4 b = *reinterpret_cast<const float4*>(sp + 4);
        *reinterpret_cast<uint4*>(WhhS + (size_t)n*512 + c8*8) = pk8(a,b);
    } else if (gid < E4){
        long j = gid - E3;                 // 0..16383
        int f = (int)(j >> 6), lane = (int)(j & 63);
        int ks = f >> 4, ig = f & 15;
        int col = lane & 15, quad = lane >> 4;
        int n = ig*16 + col;
        int k0 = ks*32 + quad*8;
        const float* sp = naW + (size_t)n*512 + k0;
        float4 a = *reinterpret_cast<const float4*>(sp);
        float4 b = *reinterpret_cast<const float4*>(sp + 4);
        *reinterpret_cast<uint4*>(nawf + j*8) = pk8(a,b);
    } else if (gid < E5){
        int n = (int)(gid - E4);
        int row = (n & 3) * 1024 + (n >> 2);
        bc[n] = qBih[row] + qBhh[row];
    }
}

// ---------------------------------------------------------------------------
// Neighbor encoder v4: one block per logical row (0..2050), both sides.
// Two K-half phases (rel, ent). Each phase: all gathers (f32 emb) issued
// upfront into a fragment-ordered 32KB LDS blob (max MLP, conflict-free
// ds_read_b128 in MFMA phase); B from frag-packed naW (L2, 4 MFMAs/load).
// ---------------------------------------------------------------------------
__global__ __launch_bounds__(256) void neighbor_v4(
    const int* __restrict__ qL, const int* __restrict__ qR,
    const int* __restrict__ sL, const int* __restrict__ sR,
    const float* __restrict__ emb,
    const u16* __restrict__ nawf,
    const float* __restrict__ naB, const float* __restrict__ nuW,
    const float* __restrict__ nuB,
    float* __restrict__ out, u16* __restrict__ out_bf)
{
    __shared__ __align__(16) u16 frg[32*512];   // 32 frags x 1KB
    __shared__ int relid[2][32];
    __shared__ int entid[2][32];
    __shared__ float logit[2][32];
    __shared__ float att[2][32];

    const int t = threadIdx.x;
    const int row = blockIdx.x;   // 0..2050
    if (t < 128){
        int s = t >> 6, j = t & 63;
        int k = j >> 1, which = j & 1;
        const int* conn;
        if (row < 2048) conn = (s ? qR : qL) + (size_t)row * 60;
        else            conn = (s ? sR : sL) + (size_t)(row - 2048) * 60;
        int id = (k < 30) ? conn[k*2 + which] : VPAD;
        if (which) entid[s][k] = id; else relid[s][k] = id;
    }
    if (t >= 128 && t < 192){ int s = (t-128) >> 5; logit[s][(t-128)&31] = 0.f; }
    __syncthreads();

    const int w = t >> 6, lane = t & 63;
    const int col = lane & 15, quad = lane >> 4;

    // decode gather unit (constant per thread across phases)
    int gc[8], gk[8], gs[8];
    #pragma unroll
    for (int i = 0; i < 8; i++){
        int idx = i*256 + t;
        gc[i] = idx & 31;            // 8-elem chunk within 256-elem half
        gk[i] = (idx >> 5) & 31;     // row 0..31
        gs[i] = idx >> 10;           // side
    }

    f32x4 acc[4][4] = {};

    #pragma unroll
    for (int p = 0; p < 2; p++){
        // gather phase p (p=0: rel, p=1: ent)
        #pragma unroll
        for (int i = 0; i < 8; i++){
            int s = gs[i], k = gk[i], c = gc[i];
            int e0 = c*8;
            int id = p ? entid[s][k] : relid[s][k];
            const float* ptr = emb + (size_t)id*256 + e0;
            float4 x = *reinterpret_cast<const float4*>(ptr);
            float4 y = *reinterpret_cast<const float4*>(ptr + 4);
            int ksl = e0 >> 5, q = (e0 >> 3) & 3;
            int mt = k >> 4, cl = k & 15;
            int ln = q*16 + cl;
            u16* dst = frg + ((((s*2 + mt)*8 + ksl)*64) + ln)*8;
            *reinterpret_cast<uint4*>(dst) = pk8(x, y);
        }
        __syncthreads();

        // MFMA phase: 8 local ks steps
        #pragma unroll
        for (int ksl = 0; ksl < 8; ksl++){
            bf16x8 a[4], b[4];
            #pragma unroll
            for (int u = 0; u < 4; u++)
                a[u] = *reinterpret_cast<const bf16x8*>(frg + (((u*8 + ksl)*64) + lane)*8);
            const int ks = p*8 + ksl;
            #pragma unroll
            for (int i = 0; i < 4; i++)
                b[i] = *reinterpret_cast<const bf16x8*>(nawf + ((size_t)(ks*16 + w*4 + i)*64 + lane)*8);
            #pragma unroll
            for (int i = 0; i < 4; i++)
                #pragma unroll
                for (int u = 0; u < 4; u++)
                    acc[u][i] = MFMA16(a[u], b[i], acc[u][i]);
        }
        __syncthreads();
    }

    // logits
    float nu[4], nbv[4];
    #pragma unroll
    for (int i = 0; i < 4; i++){
        int n = (w*4 + i)*16 + col;
        nu[i] = nuW[n]; nbv[i] = naB[n];
    }
    #pragma unroll
    for (int u = 0; u < 4; u++){
        int s = u >> 1, mt = u & 1;
        #pragma unroll
        for (int r = 0; r < 4; r++){
            int m = mt*16 + quad*4 + r;
            float v = 0.f;
            #pragma unroll
            for (int i = 0; i < 4; i++)
                v += ftanh(acc[u][i][r] + nbv[i]) * nu[i];
            v += __shfl_xor(v, 1); v += __shfl_xor(v, 2);
            v += __shfl_xor(v, 4); v += __shfl_xor(v, 8);
            if (col == 0 && m < 30) atomicAdd(&logit[s][m], v);
        }
    }
    __syncthreads();

    if (t < 2){
        const int s = t;
        const float nub = nuB[0];
        float mx = -1e30f;
        float lg[30];
        #pragma unroll
        for (int k = 0; k < 30; k++){
            float L = logit[s][k] + nub;
            lg[k] = L; mx = fmaxf(mx, L);
        }
        float sm = 0.f;
        #pragma unroll
        for (int k = 0; k < 30; k++){ float e = __expf(lg[k]-mx); att[s][k] = e; sm += e; }
        float inv = 1.f / sm;
        #pragma unroll
        for (int k = 0; k < 30; k++) att[s][k] *= inv;
    }
    __syncthreads();

    // agg: thread t = column e (0..255), both sides; ent rows are L2-hot
    const int e = t;
    #pragma unroll
    for (int s = 0; s < 2; s++){
        float agg = 0.f;
        #pragma unroll
        for (int k = 0; k < 30; k++){
            int id = entid[s][k];
            agg += att[s][k] * emb[(size_t)id*256 + e];
        }
        float r = ftanh(agg);
        size_t oi = (size_t)row*512 + s*256 + e;
        out[oi] = r;
        out_bf[oi] = f2b(r);
    }
}

// ---------------------------------------------------------------------------
// gemm_tn: C[m,n] = act( A[m,:]·B[n,:] + bias[n] (+addD[m,n]) )
// A bf16 [M x lda], B bf16 [N x ldb]. 128x64 tile, 4 waves of 64x32.
// ---------------------------------------------------------------------------
__global__ __launch_bounds__(256) void gemm_tn(
    const u16* __restrict__ A, int lda,
    const u16* __restrict__ B, int ldb,
    const float* __restrict__ bias,
    const float* __restrict__ addD, int ldd,
    float* __restrict__ Cf, u16* __restrict__ Cbf, int ldc,
    int K, int relu)
{
    __shared__ __align__(16) u16 As[128][72];
    __shared__ __align__(16) u16 Bs[64][72];
    const int t = threadIdx.x;
    const int m0 = blockIdx.y * 128, n0 = blockIdx.x * 64;
    const int w = t >> 6, lane = t & 63;
    const int col = lane & 15, quad = lane >> 4;
    const int wm = (w & 1) * 64, wn = (w >> 1) * 32;

    int arow[4], aseg[4], brow[2], bseg[2];
    #pragma unroll
    for (int i = 0; i < 4; i++){
        int idx = i*256 + t; arow[i] = idx >> 3; aseg[i] = (idx & 7) * 8;
    }
    #pragma unroll
    for (int i = 0; i < 2; i++){
        int idx = i*256 + t; brow[i] = idx >> 3; bseg[i] = (idx & 7) * 8;
    }

    f32x4 acc[4][2] = {};

    const int KC = K >> 6;
    for (int kc = 0; kc < KC; kc++){
        uint4 av[4], bv[2];
        #pragma unroll
        for (int i = 0; i < 4; i++)
            av[i] = *reinterpret_cast<const uint4*>(A + (size_t)(m0 + arow[i])*lda + kc*64 + aseg[i]);
        #pragma unroll
        for (int i = 0; i < 2; i++)
            bv[i] = *reinterpret_cast<const uint4*>(B + (size_t)(n0 + brow[i])*ldb + kc*64 + bseg[i]);
        __syncthreads();
        #pragma unroll
        for (int i = 0; i < 4; i++)
            *reinterpret_cast<uint4*>(&As[arow[i]][aseg[i]]) = av[i];
        #pragma unroll
        for (int i = 0; i < 2; i++)
            *reinterpret_cast<uint4*>(&Bs[brow[i]][bseg[i]]) = bv[i];
        __syncthreads();
        #pragma unroll
        for (int ks = 0; ks < 2; ks++){
            const int k0 = ks*32 + quad*8;
            bf16x8 af[4], bf[2];
            #pragma unroll
            for (int i = 0; i < 4; i++) af[i] = *reinterpret_cast<const bf16x8*>(&As[wm + i*16 + col][k0]);
            #pragma unroll
            for (int j = 0; j < 2; j++) bf[j] = *reinterpret_cast<const bf16x8*>(&Bs[wn + j*16 + col][k0]);
            #pragma unroll
            for (int i = 0; i < 4; i++)
                #pragma unroll
                for (int j = 0; j < 2; j++)
                    acc[i][j] = MFMA16(af[i], bf[j], acc[i][j]);
        }
    }

    #pragma unroll
    for (int j = 0; j < 2; j++){
        int n = n0 + wn + j*16 + col;
        float bj = bias[n];
        #pragma unroll
        for (int i = 0; i < 4; i++){
            #pragma unroll
            for (int r = 0; r < 4; r++){
                int m = m0 + wm + i*16 + quad*4 + r;
                float v = acc[i][j][r] + bj;
                if (addD) v += addD[(size_t)m*ldd + n];
                if (relu) v = fmaxf(v, 0.f);
                if (Cf)  Cf[(size_t)m*ldc + n] = v;
                if (Cbf) Cbf[(size_t)m*ldc + n] = f2b(v);
            }
        }
    }
}

// ---------------------------------------------------------------------------
// LayerNorm(Z + X), ddof=1, eps on sigma. One wave per row; 2051 rows.
// ---------------------------------------------------------------------------
__global__ __launch_bounds__(256) void ln_kernel(
    const float* __restrict__ Z, const float* __restrict__ X, int N, int nquery,
    const float* __restrict__ lnA, const float* __restrict__ lnB,
    float* __restrict__ Y, u16* __restrict__ Ybf, float* __restrict__ Ycopy)
{
    const int wv = threadIdx.x >> 6, lane = threadIdx.x & 63;
    const int row = blockIdx.x * 4 + wv;
    if (row >= N) return;
    const float* z = Z + (size_t)row * 512;
    const float* x = X + (size_t)row * 512;
    float v[8];
    float s = 0.f, ss = 0.f;
    {
        float4 z0 = *reinterpret_cast<const float4*>(z + lane*8);
        float4 z1 = *reinterpret_cast<const float4*>(z + lane*8 + 4);
        float4 x0 = *reinterpret_cast<const float4*>(x + lane*8);
        float4 x1 = *reinterpret_cast<const float4*>(x + lane*8 + 4);
        v[0]=z0.x+x0.x; v[1]=z0.y+x0.y; v[2]=z0.z+x0.z; v[3]=z0.w+x0.w;
        v[4]=z1.x+x1.x; v[5]=z1.y+x1.y; v[6]=z1.z+x1.z; v[7]=z1.w+x1.w;
    }
    #pragma unroll
    for (int u = 0; u < 8; u++){ s += v[u]; ss += v[u]*v[u]; }
    #pragma unroll
    for (int d = 1; d < 64; d <<= 1){
        s  += __shfl_xor(s, d);
        ss += __shfl_xor(ss, d);
    }
    float mu  = s * (1.f/512.f);
    float var = (ss - 512.f*mu*mu) * (1.f/511.f);
    float sd  = sqrtf(fmaxf(var, 0.f));
    float inv = 1.f / (sd + 1e-3f);
    float o[8];
    #pragma unroll
    for (int u = 0; u < 8; u++){
        int e = lane*8 + u;
        o[u] = (v[u] - mu) * inv * lnA[e] + lnB[e];
    }
    float* yr = Y + (size_t)row*512 + lane*8;
    *reinterpret_cast<float4*>(yr)     = make_float4(o[0],o[1],o[2],o[3]);
    *reinterpret_cast<float4*>(yr + 4) = make_float4(o[4],o[5],o[6],o[7]);
    if (row < nquery){
        uint4 p;
        p.x = pk2(o[0],o[1]); p.y = pk2(o[2],o[3]);
        p.z = pk2(o[4],o[5]); p.w = pk2(o[6],o[7]);
        *reinterpret_cast<uint4*>(Ybf + (size_t)row*512 + lane*8) = p;
        float* cr = Ycopy + (size_t)row*512 + lane*8;
        *reinterpret_cast<float4*>(cr)     = make_float4(o[0],o[1],o[2],o[3]);
        *reinterpret_cast<float4*>(cr + 4) = make_float4(o[4],o[5],o[6],o[7]);
    }
}

// ---------------------------------------------------------------------------
// Small LSTM cell (D=512, batch=1): 128 blocks x 4 d, one wave per d
// ---------------------------------------------------------------------------
__global__ __launch_bounds__(256) void lstm_small(
    const float* __restrict__ x, const float* __restrict__ hin,
    float* __restrict__ c,
    const float* __restrict__ Wih, const float* __restrict__ Whh,
    const float* __restrict__ bih, const float* __restrict__ bhh,
    float* __restrict__ hout)
{
    __shared__ float xs[512], hs[512];
    __shared__ float gbuf[4][4];
    const int t = threadIdx.x;
    for (int i = t; i < 512; i += 256){ xs[i] = x[i]; hs[i] = hin[i]; }
    __syncthreads();

    const int wd = t >> 6;
    const int lane = t & 63;
    const int g = lane >> 4, p = lane & 15;
    const int d = blockIdx.x*4 + wd;
    const int j = g*512 + d;
    const float4* wi = reinterpret_cast<const float4*>(Wih + (size_t)j*512) + p*8;
    const float4* wh = reinterpret_cast<const float4*>(Whh + (size_t)j*512) + p*8;
    float acc = 0.f;
    #pragma unroll
    for (int q = 0; q < 8; q++){
        float4 wv = wi[q];
        const int kb = p*32 + q*4;
        acc += xs[kb]*wv.x + xs[kb+1]*wv.y + xs[kb+2]*wv.z + xs[kb+3]*wv.w;
        float4 vv = wh[q];
        acc += hs[kb]*vv.x + hs[kb+1]*vv.y + hs[kb+2]*vv.z + hs[kb+3]*vv.w;
    }
    acc += __shfl_xor(acc, 1); acc += __shfl_xor(acc, 2);
    acc += __shfl_xor(acc, 4); acc += __shfl_xor(acc, 8);
    if (p == 0) gbuf[wd][g] = acc + bih[j] + bhh[j];
    __syncthreads();
    if (t < 4){
        int dd = blockIdx.x*4 + t;
        float iv = gbuf[t][0], fv = gbuf[t][1], gv = gbuf[t][2], ov = gbuf[t][3];
        float cn = sigf(fv)*c[dd] + sigf(iv)*ftanh(gv);
        float hn = sigf(ov)*ftanh(cn);
        c[dd] = cn; hout[dd] = hn;
    }
}

// ---------------------------------------------------------------------------
// ae_loss + sge_enc (singleton softmax == 1)
// ---------------------------------------------------------------------------
__global__ __launch_bounds__(256) void finalize_kernel(
    const float* __restrict__ sg, const float* __restrict__ enc,
    const float* __restrict__ dec, float* __restrict__ sgeenc,
    float* __restrict__ outp)
{
    __shared__ float red[4];
    const int t = threadIdx.x;
    float s = 0.f;
    for (int i = t; i < 1536; i += 256){ float d = sg[i] - dec[i]; s += d*d; }
    s += __shfl_xor(s,1); s += __shfl_xor(s,2); s += __shfl_xor(s,4);
    s += __shfl_xor(s,8); s += __shfl_xor(s,16); s += __shfl_xor(s,32);
    if ((t & 63) == 0) red[t>>6] = s;
    __syncthreads();
    if (t == 0){
        float tot = (red[0]+red[1]+red[2]+red[3]) * (1.f/1536.f);
        outp[2048] = tot;
    }
    for (int d = t; d < 512; d += 256){
        float v = sg[d] + enc[d] + sg[512+d] + enc[512+d] + sg[1024+d] + enc[1024+d];
        sgeenc[d] = v;
        outp[2049 + d] = v;
    }
}

// ---------------------------------------------------------------------------
// wvec[n'] = sum_j sge[j] * qWhh[(n'&3)*1024 + (n'>>2), 512+j]
// ---------------------------------------------------------------------------
__global__ __launch_bounds__(256) void wvec_kernel(
    const float* __restrict__ qWhh, const float* __restrict__ sge,
    float* __restrict__ wvec)
{
    __shared__ float ss[512];
    const int t = threadIdx.x;
    for (int i = t; i < 512; i += 256) ss[i] = sge[i];
    __syncthreads();
    const int n = blockIdx.x * 256 + t;
    const int row = (n & 3) * 1024 + (n >> 2);
    const float4* w = reinterpret_cast<const float4*>(qWhh + (size_t)row*1024 + 512);
    float acc = 0.f;
    for (int kc = 0; kc < 128; kc++){
        float4 wv = w[kc];
        const int kb = kc*4;
        acc += ss[kb]*wv.x + ss[kb+1]*wv.y + ss[kb+2]*wv.z + ss[kb+3]*wv.w;
    }
    wvec[n] = acc;
}

// ---------------------------------------------------------------------------
// Gate math on packed G: g4 = (i,f,g,o) at G[b*2048 + 4d]
// ---------------------------------------------------------------------------
__global__ __launch_bounds__(256) void gate_kernel(
    const float* __restrict__ G, const float* __restrict__ qg,
    float* __restrict__ c, u16* __restrict__ h_bf)
{
    const int idx = blockIdx.x * 256 + threadIdx.x;
    const int b = idx >> 9, d = idx & 511;
    float4 g4 = *reinterpret_cast<const float4*>(G + (size_t)b*2048 + d*4);
    float cn = sigf(g4.y)*c[idx] + sigf(g4.x)*ftanh(g4.z);
    float hn = qg[idx] + sigf(g4.w)*ftanh(cn);
    c[idx] = cn; h_bf[idx] = f2b(hn);
}

// ---------------------------------------------------------------------------
// matching_scores[b] = dot(h[b], sge_enc)
// ---------------------------------------------------------------------------
__global__ __launch_bounds__(256) void scores_kernel(
    const u16* __restrict__ h, const float* __restrict__ sge,
    float* __restrict__ out)
{
    const int wave = threadIdx.x >> 6, lane = threadIdx.x & 63;
    const int row = blockIdx.x * 4 + wave;
    const u16* hr = h + (size_t)row * 512;
    float s = 0.f;
    for (int i = lane; i < 512; i += 64) s += b2f(hr[i]) * sge[i];
    s += __shfl_xor(s,1); s += __shfl_xor(s,2); s += __shfl_xor(s,4);
    s += __shfl_xor(s,8); s += __shfl_xor(s,16); s += __shfl_xor(s,32);
    if (lane == 0) out[row] = s;
}

// ---------------------------------------------------------------------------
extern "C" void kernel_launch(void* const* d_in, const int* in_sizes, int n_in,
                              void* d_out, int out_size, void* d_ws, size_t ws_size,
                              hipStream_t stream)
{
    (void)in_sizes; (void)n_in; (void)out_size; (void)ws_size;

    const int* qlc = (const int*)d_in[2];
    const int* qrc = (const int*)d_in[4];
    const int* slc = (const int*)d_in[6];
    const int* src = (const int*)d_in[8];
    const float* emb = (const float*)d_in[10];
    const float* naW = (const float*)d_in[11];
    const float* naB = (const float*)d_in[12];
    const float* nuW = (const float*)d_in[13];
    const float* nuB = (const float*)d_in[14];
    const float* p1W = (const float*)d_in[15], *p1b = (const float*)d_in[16];
    const float* p2W = (const float*)d_in[17], *p2b = (const float*)d_in[18];
    const float* lnA = (const float*)d_in[19], *lnB = (const float*)d_in[20];
    const float* eWih = (const float*)d_in[21], *eWhh = (const float*)d_in[22];
    const float* eBih = (const float*)d_in[23], *eBhh = (const float*)d_in[24];
    const float* dWih = (const float*)d_in[25], *dWhh = (const float*)d_in[26];
    const float* dBih = (const float*)d_in[27], *dBhh = (const float*)d_in[28];
    const float* qWih = (const float*)d_in[33], *qWhh = (const float*)d_in[34];
    const float* qBih = (const float*)d_in[35], *qBhh = (const float*)d_in[36];
    float* out = (float*)d_out;

    float* w = (float*)d_ws;
    size_t off = 0;
    auto alloc = [&](size_t nelem){ float* p = w + off; off += nelem; return p; };
    float* qn    = alloc(2176ull*512);   // neighbor f32 (2051 rows used)
    float* qg    = alloc(2176ull*512);   // query_g f32 (+ sg rows 2048..2050)
    float* enc   = alloc(1536);
    float* dec   = alloc(1536);
    float* zc    = alloc(1024);
    float* sgee  = alloc(512);
    float* wv    = alloc(2048);
    float* bc    = alloc(2048);
    float* nawfF = alloc(65536);         // 131072 u16 frag-packed naW
    float* base  = alloc(2048ull*2048);  // + Zq, qn_bf aliases
    float* G     = alloc(2048ull*2048);  // + Hq_bf, qg_bf aliases
    float* cb    = alloc(2048ull*512);
    float* hbfF  = alloc(524288);        // h bf16
    float* p1WbF = alloc(262144);
    float* p2WbF = alloc(262144);
    float* WihSF = alloc(524288);
    float* WhhSF = alloc(524288);

    u16* nawf   = (u16*)nawfF;
    u16* p1Wb   = (u16*)p1WbF;
    u16* p2Wb   = (u16*)p2WbF;
    u16* WihSel = (u16*)WihSF;
    u16* WhhSel = (u16*)WhhSF;
    u16* h_bf   = (u16*)hbfF;
    float* Zq   = base;                       // 2176x512 f32
    u16* qn_bf  = (u16*)(base + 2097152);     // 2176x512 u16
    u16* Hq_bf  = (u16*)G;                    // 2176x1024 u16
    u16* qg_bf  = (u16*)(G + 2097152);        // 2176x512 u16 (2048 used)
    float* sg   = qg + 2048ull*512;
    float* zbuf = zc;
    float* cst  = zc + 512;

    hipMemsetAsync(zc, 0, 1024*sizeof(float), stream);
    hipMemsetAsync(cb, 0, 2048ull*512*sizeof(float), stream);

    // weight preprocessing (no emb conversion)
    prep_kernel<<<2120, 256, 0, stream>>>(p1W, p2W, naW, qWih, qWhh, qBih, qBhh,
                                          p1Wb, p2Wb, nawf, WihSel, WhhSel, bc);

    // neighbor encoder: 2051 rows (2048 query + 3 support), both sides
    neighbor_v4<<<2051, 256, 0, stream>>>(qlc, qrc, slc, src, emb,
                                          nawf, naB, nuW, nuB, qn, qn_bf);

    // support encoder fused over 2051 rows: H=relu(X@p1W^T+b); Z=H@p2W^T+b; LN
    gemm_tn<<<dim3(16,17), 256, 0, stream>>>(qn_bf, 512, p1Wb, 512, p1b, nullptr, 0,
                                             nullptr, Hq_bf, 1024, 512, 1);
    gemm_tn<<<dim3(8,17), 256, 0, stream>>>(Hq_bf, 1024, p2Wb, 1024, p2b, nullptr, 0,
                                            Zq, nullptr, 512, 1024, 0);
    ln_kernel<<<513, 256, 0, stream>>>(Zq, qn, 2051, 2048, lnA, lnB, qg, qg_bf, out + 2561);

    // set autoencoder
    lstm_small<<<128, 256, 0, stream>>>(sg,        zbuf,      cst, eWih, eWhh, eBih, eBhh, enc);
    lstm_small<<<128, 256, 0, stream>>>(sg + 512,  enc,       cst, eWih, eWhh, eBih, eBhh, enc + 512);
    lstm_small<<<128, 256, 0, stream>>>(sg + 1024, enc + 512, cst, eWih, eWhh, eBih, eBhh, enc + 1024);
    lstm_small<<<128, 256, 0, stream>>>(enc + 1024, enc + 1024, cst, dWih, dWhh, dBih, dBhh, dec);
    lstm_small<<<128, 256, 0, stream>>>(dec,        dec,        cst, dWih, dWhh, dBih, dBhh, dec + 512);
    lstm_small<<<128, 256, 0, stream>>>(dec + 512,  dec + 512,  cst, dWih, dWhh, dBih, dBhh, dec + 1024);

    finalize_kernel<<<1, 256, 0, stream>>>(sg, enc, dec, sgee, out);
    wvec_kernel<<<8, 256, 0, stream>>>(qWhh, sgee, wv);

    // query encoder: base = qg@WihSel^T + bc; 4 steps (live half only)
    gemm_tn<<<dim3(32,16), 256, 0, stream>>>(qg_bf, 512, WihSel, 512, bc, nullptr, 0,
                                             base, nullptr, 2048, 512, 0);
    gate_kernel<<<4096, 256, 0, stream>>>(base, qg, cb, h_bf);
    for (int s = 0; s < 3; s++){
        gemm_tn<<<dim3(32,16), 256, 0, stream>>>(h_bf, 512, WhhSel, 512, wv, base, 2048,
                                                 G, nullptr, 2048, 512, 0);
        gate_kernel<<<4096, 256, 0, stream>>>(G, qg, cb, h_bf);
    }

    scores_kernel<<<512, 256, 0, stream>>>(h_bf, sgee, out);
}